// Round 16
// baseline (286.064 us; speedup 1.0000x reference)
//
#include <hip/hip_runtime.h>
#include <hip/hip_bf16.h>

namespace {
constexpr int D       = 128;
constexpr int K       = 1024;
constexpr int M_TOTAL = 65536;   // 16 * 4096
constexpr int BM      = 128;     // rows per score-block: 4 waves x 32 rows
constexpr int NCT     = K / 16;  // 64 code-tiles of 16 codes
constexpr float TAU   = 5.0e-5f; // covers numpy-fp32 quantization span + scorer err
// d_ws layout
constexpr size_t WS_CN  = 0;                 // float[1024]         (4 KB)
constexpr size_t WS_BH  = 4096;              // short[131072]       (256 KB)
constexpr size_t WS_BL  = 4096 + 262144;     // short[131072]       (256 KB)
constexpr size_t WS_REQ = 4096 + 2 * 262144; // 528,384 B (confirmed available, R11-R15)
}

typedef short bf16x8 __attribute__((ext_vector_type(8)));
typedef float f32x4  __attribute__((ext_vector_type(4)));

static __device__ __forceinline__ unsigned short bfbits(float x) {
  __hip_bfloat16 h = __float2bfloat16(x);   // RNE
  return *reinterpret_cast<unsigned short*>(&h);
}
static __device__ __forceinline__ float bfhi2f(unsigned short h) {
  return __uint_as_float(((unsigned)h) << 16);
}
static __device__ __forceinline__ void split8(float4 a, float4 b,
                                              bf16x8& ph, bf16x8& pl) {
  float v[8] = {a.x, a.y, a.z, a.w, b.x, b.y, b.z, b.w};
#pragma unroll
  for (int e = 0; e < 8; ++e) {
    unsigned short h = bfbits(v[e]);
    unsigned short l = bfbits(v[e] - bfhi2f(h));
    ph[e] = (short)h;
    pl[e] = (short)l;
  }
}

// ---------------- prep 1: Cn[k] = numpy-pairwise fp32 sum of cb[k,d]^2 ----------------
__global__ void vq_prep(const float* __restrict__ cb, float* __restrict__ Cn) {
  int k = blockIdx.x * 256 + threadIdx.x;
  if (k >= K) return;
  const float* c = cb + (size_t)k * D;
  float r8[8];
#pragma unroll
  for (int j = 0; j < 8; ++j) r8[j] = __fmul_rn(c[j], c[j]);
  for (int i = 8; i < D; i += 8) {
#pragma unroll
    for (int j = 0; j < 8; ++j)
      r8[j] = __fadd_rn(r8[j], __fmul_rn(c[i + j], c[i + j]));
  }
  Cn[k] = __fadd_rn(__fadd_rn(__fadd_rn(r8[0], r8[1]), __fadd_rn(r8[2], r8[3])),
                    __fadd_rn(__fadd_rn(r8[4], r8[5]), __fadd_rn(r8[6], r8[7])));
}

// ---------------- prep 2: codebook -> hi/lo bf16 planes, fragment-linear (validated) ----
__global__ void vq_frag(const float* __restrict__ cb,
                        short* __restrict__ Bh, short* __restrict__ Bl) {
  int g = blockIdx.x * 256 + threadIdx.x;           // 0 .. 16383
  int code = (g >> 8) * 16 + (g & 15);
  int d0   = ((g >> 6) & 3) * 32 + ((g >> 4) & 3) * 8;
  const float* p = cb + (size_t)code * D + d0;
  float4 a = *reinterpret_cast<const float4*>(p);
  float4 b = *reinterpret_cast<const float4*>(p + 4);
  bf16x8 ph, pl;
  split8(a, b, ph, pl);
  *reinterpret_cast<bf16x8*>(Bh + (size_t)g * 8) = ph;
  *reinterpret_cast<bf16x8*>(Bl + (size_t)g * 8) = pl;
}

// ---------------- kernel 1: SCORE — R15 pipeline verbatim, writes idx + gap ----------
__global__ __launch_bounds__(256, 2) void vq_score(
    const float* __restrict__ z, const float* __restrict__ Cn,
    const short* __restrict__ BhG, const short* __restrict__ BlG,
    float* __restrict__ out_iF, float* __restrict__ out_gap) {
  __shared__ __align__(16) short Bbuf[4][8][512];   // 32 KB
  __shared__ float CnS[K];                           // 4 KB

  const int t    = threadIdx.x;
  const int wave = t >> 6;
  const int lane = t & 63;
  const int col  = lane & 15;
  const int baseRow = blockIdx.x * BM;

  for (int i = t; i < K; i += 256) CnS[i] = Cn[i];

  bf16x8 ah[2][4], al[2][4];
#pragma unroll
  for (int set = 0; set < 2; ++set) {
    const float* zL = z + (size_t)(baseRow + wave * 32 + set * 16 + col) * D + (lane >> 4) * 8;
#pragma unroll
    for (int ks = 0; ks < 4; ++ks) {
      float4 a = *reinterpret_cast<const float4*>(zL + ks * 32);
      float4 b = *reinterpret_cast<const float4*>(zL + ks * 32 + 4);
      split8(a, b, ah[set][ks], al[set][ks]);
    }
  }

  float s1[2][4], s2[2][4]; int i1[2][4];
#pragma unroll
  for (int s = 0; s < 2; ++s)
#pragma unroll
    for (int i = 0; i < 4; ++i) {
      s1[s][i] = 3.402823466e+38f; s2[s][i] = 3.402823466e+38f; i1[s][i] = 0;
    }

#define STAGE(ct_, bi_)                                                             \
  { _Pragma("unroll")                                                               \
    for (int i_ = 0; i_ < 2; ++i_) {                                                \
      int c_  = wave * 2 + i_;                                                      \
      int p_  = c_ >> 2, ks_ = c_ & 3;                                              \
      const short* gsrc_ = (p_ ? BlG : BhG) +                                       \
                           (size_t)(((ct_) * 4 + ks_) * 64 + lane) * 8;             \
      __builtin_amdgcn_global_load_lds(                                             \
          (const __attribute__((address_space(1))) void*)gsrc_,                     \
          (__attribute__((address_space(3))) void*)&Bbuf[bi_][c_][0], 16, 0, 0);    \
    } }

#define COMP(bi_, ct_)                                                              \
  { bf16x8 bh_c[4], bl_c[4];                                                        \
    _Pragma("unroll")                                                               \
    for (int ks_ = 0; ks_ < 4; ++ks_) {                                             \
      bh_c[ks_] = *reinterpret_cast<const bf16x8*>(&Bbuf[bi_][ks_][lane * 8]);      \
      bl_c[ks_] = *reinterpret_cast<const bf16x8*>(&Bbuf[bi_][4 + ks_][lane * 8]);  \
    }                                                                               \
    const int code_ = (ct_) * 16 + col;                                             \
    const float cn_ = CnS[code_];                                                   \
    __builtin_amdgcn_s_setprio(1);                                                  \
    _Pragma("unroll")                                                               \
    for (int set_ = 0; set_ < 2; ++set_) {                                          \
      f32x4 aA = (f32x4){0.f,0.f,0.f,0.f};                                          \
      f32x4 aB = (f32x4){0.f,0.f,0.f,0.f};                                          \
      f32x4 aC = (f32x4){0.f,0.f,0.f,0.f};                                          \
      _Pragma("unroll")                                                             \
      for (int ks_ = 0; ks_ < 4; ++ks_) {                                           \
        aA = __builtin_amdgcn_mfma_f32_16x16x32_bf16(ah[set_][ks_], bh_c[ks_], aA, 0,0,0); \
        aB = __builtin_amdgcn_mfma_f32_16x16x32_bf16(ah[set_][ks_], bl_c[ks_], aB, 0,0,0); \
        aC = __builtin_amdgcn_mfma_f32_16x16x32_bf16(al[set_][ks_], bh_c[ks_], aC, 0,0,0); \
      }                                                                             \
      _Pragma("unroll")                                                             \
      for (int reg_ = 0; reg_ < 4; ++reg_) {                                        \
        float S = fmaf(-2.0f, (aA[reg_] + aB[reg_]) + aC[reg_], cn_);               \
        if (S < s1[set_][reg_]) { s2[set_][reg_] = s1[set_][reg_];                  \
                                  s1[set_][reg_] = S; i1[set_][reg_] = code_; }     \
        else if (S < s2[set_][reg_]) { s2[set_][reg_] = S; }                        \
      }                                                                             \
    }                                                                               \
    __builtin_amdgcn_s_setprio(0); }

#define PHASE(t_, bi_)                                                              \
  { asm volatile("s_waitcnt vmcnt(4)" ::: "memory");                                \
    __builtin_amdgcn_s_barrier();                                                   \
    __builtin_amdgcn_sched_barrier(0);                                              \
    COMP(bi_, t_);                                                                  \
    STAGE(((t_) + 3) & 63, ((bi_) + 3) & 3); }

  __syncthreads();   // CnS visible
  STAGE(0, 0); STAGE(1, 1); STAGE(2, 2);
  for (int g = 0; g < NCT; g += 4) {
    PHASE(g + 0, 0);
    PHASE(g + 1, 1);
    PHASE(g + 2, 2);
    PHASE(g + 3, 3);
  }
#undef PHASE
#undef STAGE
#undef COMP

  // cross-lane (16-col group) min1/min2 merge
#pragma unroll
  for (int m = 1; m < 16; m <<= 1) {
#pragma unroll
    for (int set = 0; set < 2; ++set)
#pragma unroll
      for (int reg = 0; reg < 4; ++reg) {
        float os1 = __shfl_xor(s1[set][reg], m, 64);
        float os2 = __shfl_xor(s2[set][reg], m, 64);
        int   oi  = __shfl_xor(i1[set][reg], m, 64);
        if (os1 < s1[set][reg]) {
          s2[set][reg] = fminf(s1[set][reg], os2);
          s1[set][reg] = os1; i1[set][reg] = oi;
        } else {
          s2[set][reg] = fminf(s2[set][reg], os1);
        }
      }
  }

  if (col == 0) {
#pragma unroll
    for (int set = 0; set < 2; ++set)
#pragma unroll
      for (int reg = 0; reg < 4; ++reg) {
        int row = wave * 32 + set * 16 + (lane >> 4) * 4 + reg;
        size_t m = (size_t)baseRow + row;
        out_iF[m]  = (float)i1[set][reg];
        out_gap[m] = s2[set][reg] - s1[set][reg];   // rescan keys off this
      }
  }
}

// ---------------- kernel 2: RESCAN — one wave per hard row, bit-exact numpy-fp32 ------
__global__ __launch_bounds__(256, 4) void vq_rescan(
    const float* __restrict__ z, const float* __restrict__ cb,
    const float* __restrict__ Cn,
    const float* __restrict__ gap, float* __restrict__ out_iF) {
  __shared__ float CnS[K];
  __shared__ int   list[256];
  __shared__ int   cnt;

  const int t  = threadIdx.x;
  const int wv = t >> 6;
  const int ln = t & 63;

  if (t == 0) cnt = 0;
  for (int i = t; i < K; i += 256) CnS[i] = Cn[i];
  __syncthreads();

  int m = blockIdx.x * 256 + t;       // grid 256 covers all 65536 rows
  if (gap[m] < TAU) { int p = atomicAdd(&cnt, 1); list[p] = m; }
  __syncthreads();
  const int n = cnt;

  for (int f = wv; f < n; f += 4) {   // one wave per hard row
    const int row = list[f];
    const float*  zp  = z + (size_t)row * D;
    const float4* zp4 = reinterpret_cast<const float4*>(zp);
    // numpy pairwise-8 A (broadcast scalar loads, redundant per lane)
    float r8[8];
#pragma unroll
    for (int j = 0; j < 8; ++j) r8[j] = __fmul_rn(zp[j], zp[j]);
    for (int i = 8; i < D; i += 8) {
#pragma unroll
      for (int j = 0; j < 8; ++j)
        r8[j] = __fadd_rn(r8[j], __fmul_rn(zp[i + j], zp[i + j]));
    }
    float A = __fadd_rn(__fadd_rn(__fadd_rn(r8[0], r8[1]), __fadd_rn(r8[2], r8[3])),
                        __fadd_rn(__fadd_rn(r8[4], r8[5]), __fadd_rn(r8[6], r8[7])));
    // lane owns 16 consecutive codes; sequential fp32 FMA chains (ascending d)
    float bd = 3.402823466e+38f; int bi = 0;
    for (int c = 0; c < 16; ++c) {
      const int k = ln * 16 + c;
      const float4* cp = reinterpret_cast<const float4*>(cb + (size_t)k * D);
      float acc = 0.f;
#pragma unroll 8
      for (int d4 = 0; d4 < 32; ++d4) {
        float4 zv = zp4[d4];
        float4 cv = cp[d4];
        acc = fmaf(zv.x, cv.x, acc); acc = fmaf(zv.y, cv.y, acc);
        acc = fmaf(zv.z, cv.z, acc); acc = fmaf(zv.w, cv.w, acc);
      }
      float dist = __fadd_rn(__fsub_rn(A, __fmul_rn(2.0f, acc)), CnS[k]);
      if (dist < bd) { bd = dist; bi = k; }   // ascending k: first index wins
    }
    // wave-wide min reduce, tie -> lower index (np.argmin first occurrence)
#pragma unroll
    for (int mm = 1; mm < 64; mm <<= 1) {
      float o  = __shfl_xor(bd, mm, 64);
      int   oi = __shfl_xor(bi, mm, 64);
      if (o < bd || (o == bd && oi < bi)) { bd = o; bi = oi; }
    }
    if (ln == 0) out_iF[row] = (float)bi;
  }
}

// ---------------- kernel 3: EPILOGUE — pure-BW gather/STE/loss (4 threads/row) --------
__global__ __launch_bounds__(256) void vq_epi(
    const float* __restrict__ z, const float* __restrict__ cb,
    const float* __restrict__ out_iF,
    float* __restrict__ out_zq, float* __restrict__ out_q,
    float* __restrict__ out_c) {
  const int t = threadIdx.x;
  const int r = t >> 2, q = t & 3;
  const size_t m = (size_t)blockIdx.x * 64 + r;   // grid 1024
  const int idx = (int)out_iF[m];
  const float4* cq = reinterpret_cast<const float4*>(cb + (size_t)idx * D);
  const float4* zr = reinterpret_cast<const float4*>(z + m * D);
  float4*       o4 = reinterpret_cast<float4*>(out_zq + m * D);
  float sum = 0.f;
#pragma unroll
  for (int e = 0; e < 8; ++e) {
    int d4 = q * 8 + e;
    float4 cv = cq[d4];
    float4 zv = zr[d4];
    float dx = cv.x - zv.x, dy = cv.y - zv.y, dz = cv.z - zv.z, dw = cv.w - zv.w;
    float4 st;
    st.x = zv.x + dx; st.y = zv.y + dy; st.z = zv.z + dz; st.w = zv.w + dw;
    o4[d4] = st;
    sum = fmaf(dx, dx, sum); sum = fmaf(dy, dy, sum);
    sum = fmaf(dz, dz, sum); sum = fmaf(dw, dw, sum);
  }
  sum += __shfl_xor(sum, 1, 64);
  sum += __shfl_xor(sum, 2, 64);
  if (q == 0) {
    float lv = sum * 0.0078125f;   // /128
    out_q[m] = lv;
    out_c[m] = lv;
  }
}

// ---------------- FALLBACK main: R4 kernel verbatim (validated, ~320 us) ---------------
__global__ __launch_bounds__(256) void vq_main_fp32(
    const float* __restrict__ z, const float* __restrict__ cb,
    const float* __restrict__ Cn,
    float* __restrict__ out_zq, float* __restrict__ out_q,
    float* __restrict__ out_c, float* __restrict__ out_i) {
  __shared__ float Zt[64 * D];
  __shared__ float Ct[64 * D];
  __shared__ float Arow[64];
  __shared__ int   idxArr[64];

  const int t  = threadIdx.x;
  const int ty = t >> 4;
  const int tx = t & 15;
  const int baseRow = blockIdx.x * 64;

  for (int s = t; s < 64 * (D / 4); s += 256) {
    int r = s >> 5, d4 = s & 31;
    float4 v = reinterpret_cast<const float4*>(z)[(size_t)(baseRow + r) * (D / 4) + d4];
    int colx = d4 ^ (r & 7);
    *reinterpret_cast<float4*>(&Zt[r * D + colx * 4]) = v;
  }
  __syncthreads();

  if (t < 64) {
    const int rs = t & 7;
    float r8[8];
#pragma unroll
    for (int j = 0; j < 8; ++j) {
      float v = Zt[t * D + (((j >> 2) ^ rs) << 2) + (j & 3)];
      r8[j] = __fmul_rn(v, v);
    }
    for (int i = 8; i < D; i += 8) {
#pragma unroll
      for (int j = 0; j < 8; ++j) {
        int d = i + j;
        float v = Zt[t * D + (((d >> 2) ^ rs) << 2) + (d & 3)];
        r8[j] = __fadd_rn(r8[j], __fmul_rn(v, v));
      }
    }
    Arow[t] = __fadd_rn(__fadd_rn(__fadd_rn(r8[0], r8[1]), __fadd_rn(r8[2], r8[3])),
                        __fadd_rn(__fadd_rn(r8[4], r8[5]), __fadd_rn(r8[6], r8[7])));
  }

  float s1[4]; int i1[4];
#pragma unroll
  for (int i = 0; i < 4; ++i) { s1[i] = 3.402823466e+38f; i1[i] = 0; }

  const int zsw = ty & 7;
  const int csw = tx & 7;

  for (int kt = 0; kt < 16; ++kt) {
    __syncthreads();
    for (int s = t; s < 64 * (D / 4); s += 256) {
      int r = s >> 5, d4 = s & 31;
      float4 v = reinterpret_cast<const float4*>(cb)[(size_t)(kt * 64 + r) * (D / 4) + d4];
      int colx = d4 ^ (r & 7);
      *reinterpret_cast<float4*>(&Ct[r * D + colx * 4]) = v;
    }
    __syncthreads();

    float acc[4][4];
#pragma unroll
    for (int i = 0; i < 4; ++i)
#pragma unroll
      for (int j = 0; j < 4; ++j) acc[i][j] = 0.f;

    for (int d4 = 0; d4 < 32; ++d4) {
      float4 za[4], cv[4];
      int zc = (d4 ^ zsw) * 4;
      int cc = (d4 ^ csw) * 4;
#pragma unroll
      for (int i = 0; i < 4; ++i)
        za[i] = *reinterpret_cast<const float4*>(&Zt[(ty + 16 * i) * D + zc]);
#pragma unroll
      for (int j = 0; j < 4; ++j)
        cv[j] = *reinterpret_cast<const float4*>(&Ct[(tx + 16 * j) * D + cc]);
#pragma unroll
      for (int i = 0; i < 4; ++i)
#pragma unroll
        for (int j = 0; j < 4; ++j) {
          acc[i][j] = fmaf(za[i].x, cv[j].x, acc[i][j]);
          acc[i][j] = fmaf(za[i].y, cv[j].y, acc[i][j]);
          acc[i][j] = fmaf(za[i].z, cv[j].z, acc[i][j]);
          acc[i][j] = fmaf(za[i].w, cv[j].w, acc[i][j]);
        }
    }

    float ch[4]; int kg[4];
#pragma unroll
    for (int j = 0; j < 4; ++j) {
      kg[j] = kt * 64 + tx + 16 * j;
      ch[j] = Cn[kg[j]];
    }
#pragma unroll
    for (int i = 0; i < 4; ++i) {
      float a = Arow[ty + 16 * i];
#pragma unroll
      for (int j = 0; j < 4; ++j) {
        float dist = __fadd_rn(__fsub_rn(a, __fmul_rn(2.0f, acc[i][j])), ch[j]);
        if (dist < s1[i]) { s1[i] = dist; i1[i] = kg[j]; }
      }
    }
  }

#pragma unroll
  for (int m = 1; m < 16; m <<= 1) {
#pragma unroll
    for (int i = 0; i < 4; ++i) {
      float os = __shfl_xor(s1[i], m, 64);
      int   oi = __shfl_xor(i1[i], m, 64);
      if (os < s1[i] || (os == s1[i] && oi < i1[i])) { s1[i] = os; i1[i] = oi; }
    }
  }

  if (tx == 0) {
#pragma unroll
    for (int i = 0; i < 4; ++i) idxArr[ty + 16 * i] = i1[i];
  }
  __syncthreads();

  {
    int r = t >> 2, q = t & 3;
    int idx = idxArr[r];
    size_t m = (size_t)baseRow + r;
    const float4* cq = reinterpret_cast<const float4*>(cb + (size_t)idx * D);
    const float4* zr = reinterpret_cast<const float4*>(z + m * D);
    float4*       o4 = reinterpret_cast<float4*>(out_zq + m * D);
    float sum = 0.f;
#pragma unroll
    for (int e = 0; e < 8; ++e) {
      int d4 = q * 8 + e;
      float4 cv = cq[d4];
      float4 zv = zr[d4];
      float dx = cv.x - zv.x, dy = cv.y - zv.y, dz = cv.z - zv.z, dw = cv.w - zv.w;
      float4 st;
      st.x = zv.x + dx; st.y = zv.y + dy; st.z = zv.z + dz; st.w = zv.w + dw;
      o4[d4] = st;
      sum = fmaf(dx, dx, sum); sum = fmaf(dy, dy, sum);
      sum = fmaf(dz, dz, sum); sum = fmaf(dw, dw, sum);
    }
    sum += __shfl_xor(sum, 1, 64);
    sum += __shfl_xor(sum, 2, 64);
    if (q == 0) {
      float lv = sum * 0.0078125f;
      out_q[m] = lv;
      out_c[m] = lv;
      out_i[m] = (float)idx;
    }
  }
}

extern "C" void kernel_launch(void* const* d_in, const int* in_sizes, int n_in,
                              void* d_out, int out_size, void* d_ws, size_t ws_size,
                              hipStream_t stream) {
  const float* z  = (const float*)d_in[0];   // [16,4096,128] fp32
  const float* cb = (const float*)d_in[1];   // [1024,128] fp32

  float* out0 = (float*)d_out;               // z_q_ste  [M,128]
  float* out1 = out0 + (size_t)M_TOTAL * D;  // quant_loss [M]
  float* out2 = out1 + M_TOTAL;              // commit_loss [M]
  float* out3 = out2 + M_TOTAL;              // indices (as float) [M]

  float* Cn = (float*)((char*)d_ws + WS_CN);
  vq_prep<<<(K + 255) / 256, 256, 0, stream>>>(cb, Cn);

  if (ws_size >= WS_REQ) {
    short* Bh = (short*)((char*)d_ws + WS_BH);
    short* Bl = (short*)((char*)d_ws + WS_BL);
    vq_frag<<<64, 256, 0, stream>>>(cb, Bh, Bl);
    // score -> rescan (gap stashed in out1) -> epilogue (overwrites out1 with loss)
    vq_score<<<M_TOTAL / BM, 256, 0, stream>>>(z, Cn, Bh, Bl, out3, out1);
    vq_rescan<<<M_TOTAL / 256, 256, 0, stream>>>(z, cb, Cn, out1, out3);
    vq_epi<<<M_TOTAL / 64, 256, 0, stream>>>(z, cb, out3, out0, out1, out2);
  } else {
    vq_main_fp32<<<M_TOTAL / 64, 256, 0, stream>>>(z, cb, Cn, out0, out1, out2, out3);
  }
}

// Round 17
// 257.405 us; speedup vs baseline: 1.1113x; 1.1113x over previous
//
#include <hip/hip_runtime.h>
#include <hip/hip_bf16.h>

namespace {
constexpr int D       = 128;
constexpr int K       = 1024;
constexpr int M_TOTAL = 65536;   // 16 * 4096
constexpr int BM      = 128;     // rows per score-block: 4 waves x 32 rows
constexpr int NCT     = K / 16;  // 64 code-tiles of 16 codes
constexpr float TAU   = 5.0e-5f; // > 2*(scorer err) + 2*(numpy quantization span)
// d_ws layout
constexpr size_t WS_CN  = 0;                 // float[1024]         (4 KB)
constexpr size_t WS_BH  = 4096;              // short[131072]       (256 KB)
constexpr size_t WS_BL  = 4096 + 262144;     // short[131072]       (256 KB)
constexpr size_t WS_REQ = 4096 + 2 * 262144; // 528,384 B (confirmed available, R11-R16)
}

typedef short bf16x8 __attribute__((ext_vector_type(8)));
typedef float f32x4  __attribute__((ext_vector_type(4)));

static __device__ __forceinline__ unsigned short bfbits(float x) {
  __hip_bfloat16 h = __float2bfloat16(x);   // RNE
  return *reinterpret_cast<unsigned short*>(&h);
}
static __device__ __forceinline__ float bfhi2f(unsigned short h) {
  return __uint_as_float(((unsigned)h) << 16);
}
static __device__ __forceinline__ void split8(float4 a, float4 b,
                                              bf16x8& ph, bf16x8& pl) {
  float v[8] = {a.x, a.y, a.z, a.w, b.x, b.y, b.z, b.w};
#pragma unroll
  for (int e = 0; e < 8; ++e) {
    unsigned short h = bfbits(v[e]);
    unsigned short l = bfbits(v[e] - bfhi2f(h));
    ph[e] = (short)h;
    pl[e] = (short)l;
  }
}
// numpy pairwise-8 row norm of 128 consecutive floats (R4-validated, bit-exact)
static __device__ __forceinline__ float np_norm128(const float* p) {
  float r8[8];
#pragma unroll
  for (int j = 0; j < 8; ++j) r8[j] = __fmul_rn(p[j], p[j]);
  for (int i = 8; i < D; i += 8) {
#pragma unroll
    for (int j = 0; j < 8; ++j)
      r8[j] = __fadd_rn(r8[j], __fmul_rn(p[i + j], p[i + j]));
  }
  return __fadd_rn(__fadd_rn(__fadd_rn(r8[0], r8[1]), __fadd_rn(r8[2], r8[3])),
                   __fadd_rn(__fadd_rn(r8[4], r8[5]), __fadd_rn(r8[6], r8[7])));
}
// sequential fp32 FMA dot (OpenBLAS order, R4-validated, bit-exact)
static __device__ __forceinline__ float np_dot128(const float4* zp4, const float4* cp4) {
  float acc = 0.f;
#pragma unroll 8
  for (int d4 = 0; d4 < 32; ++d4) {
    float4 zv = zp4[d4];
    float4 cv = cp4[d4];
    acc = fmaf(zv.x, cv.x, acc); acc = fmaf(zv.y, cv.y, acc);
    acc = fmaf(zv.z, cv.z, acc); acc = fmaf(zv.w, cv.w, acc);
  }
  return acc;
}

// ---------------- prep 1: Cn + zero full-rescan counter ----------------
__global__ void vq_prep(const float* __restrict__ cb, float* __restrict__ Cn,
                        int* __restrict__ cnt) {
  int k = blockIdx.x * 256 + threadIdx.x;
  if (k == 0) *cnt = 0;
  if (k >= K) return;
  const float* c = cb + (size_t)k * D;
  Cn[k] = np_norm128(c);
}

// ---------------- prep 2: codebook -> hi/lo bf16 planes, fragment-linear (validated) ----
__global__ void vq_frag(const float* __restrict__ cb,
                        short* __restrict__ Bh, short* __restrict__ Bl) {
  int g = blockIdx.x * 256 + threadIdx.x;           // 0 .. 16383
  int code = (g >> 8) * 16 + (g & 15);
  int d0   = ((g >> 6) & 3) * 32 + ((g >> 4) & 3) * 8;
  const float* p = cb + (size_t)code * D + d0;
  float4 a = *reinterpret_cast<const float4*>(p);
  float4 b = *reinterpret_cast<const float4*>(p + 4);
  bf16x8 ph, pl;
  split8(a, b, ph, pl);
  *reinterpret_cast<bf16x8*>(Bh + (size_t)g * 8) = ph;
  *reinterpret_cast<bf16x8*>(Bl + (size_t)g * 8) = pl;
}

// 4-deep sorted insert of (S, code): booleans from OLD values, update 4->1
#define INS4(S_, C_, se_, re_)                                                      \
  { bool l1 = (S_) < s1v[se_][re_]; bool l2 = (S_) < s2v[se_][re_];                 \
    bool l3 = (S_) < s3v[se_][re_]; bool l4 = (S_) < s4v[se_][re_];                 \
    s4v[se_][re_] = l4 ? (l3 ? s3v[se_][re_] : (S_)) : s4v[se_][re_];               \
    i4v[se_][re_] = l4 ? (l3 ? i3v[se_][re_] : (C_)) : i4v[se_][re_];               \
    s3v[se_][re_] = l3 ? (l2 ? s2v[se_][re_] : (S_)) : s3v[se_][re_];               \
    i3v[se_][re_] = l3 ? (l2 ? i2v[se_][re_] : (C_)) : i3v[se_][re_];               \
    s2v[se_][re_] = l2 ? (l1 ? s1v[se_][re_] : (S_)) : s2v[se_][re_];               \
    i2v[se_][re_] = l2 ? (l1 ? i1v[se_][re_] : (C_)) : i2v[se_][re_];               \
    s1v[se_][re_] = l1 ? (S_) : s1v[se_][re_];                                      \
    i1v[se_][re_] = l1 ? (C_) : i1v[se_][re_]; }

// ---------------- kernel 1: SCORE — R15 pipeline, top-4 tracking ----------
__global__ __launch_bounds__(256, 2) void vq_score(
    const float* __restrict__ z, const float* __restrict__ Cn,
    const short* __restrict__ BhG, const short* __restrict__ BlG,
    float* __restrict__ out_iF, float* __restrict__ gI2, float* __restrict__ gI3,
    float* __restrict__ gG2, float* __restrict__ gG4) {
  __shared__ __align__(16) short Bbuf[4][8][512];   // 32 KB
  __shared__ float CnS[K];                           // 4 KB

  const int t    = threadIdx.x;
  const int wave = t >> 6;
  const int lane = t & 63;
  const int col  = lane & 15;
  const int baseRow = blockIdx.x * BM;

  for (int i = t; i < K; i += 256) CnS[i] = Cn[i];

  bf16x8 ah[2][4], al[2][4];
#pragma unroll
  for (int set = 0; set < 2; ++set) {
    const float* zL = z + (size_t)(baseRow + wave * 32 + set * 16 + col) * D + (lane >> 4) * 8;
#pragma unroll
    for (int ks = 0; ks < 4; ++ks) {
      float4 a = *reinterpret_cast<const float4*>(zL + ks * 32);
      float4 b = *reinterpret_cast<const float4*>(zL + ks * 32 + 4);
      split8(a, b, ah[set][ks], al[set][ks]);
    }
  }

  float s1v[2][4], s2v[2][4], s3v[2][4], s4v[2][4];
  int   i1v[2][4], i2v[2][4], i3v[2][4], i4v[2][4];
#pragma unroll
  for (int s = 0; s < 2; ++s)
#pragma unroll
    for (int i = 0; i < 4; ++i) {
      s1v[s][i] = s2v[s][i] = s3v[s][i] = s4v[s][i] = 3.402823466e+38f;
      i1v[s][i] = i2v[s][i] = i3v[s][i] = i4v[s][i] = 0;
    }

#define STAGE(ct_, bi_)                                                             \
  { _Pragma("unroll")                                                               \
    for (int i_ = 0; i_ < 2; ++i_) {                                                \
      int c_  = wave * 2 + i_;                                                      \
      int p_  = c_ >> 2, ks_ = c_ & 3;                                              \
      const short* gsrc_ = (p_ ? BlG : BhG) +                                       \
                           (size_t)(((ct_) * 4 + ks_) * 64 + lane) * 8;             \
      __builtin_amdgcn_global_load_lds(                                             \
          (const __attribute__((address_space(1))) void*)gsrc_,                     \
          (__attribute__((address_space(3))) void*)&Bbuf[bi_][c_][0], 16, 0, 0);    \
    } }

#define COMP(bi_, ct_)                                                              \
  { bf16x8 bh_c[4], bl_c[4];                                                        \
    _Pragma("unroll")                                                               \
    for (int ks_ = 0; ks_ < 4; ++ks_) {                                             \
      bh_c[ks_] = *reinterpret_cast<const bf16x8*>(&Bbuf[bi_][ks_][lane * 8]);      \
      bl_c[ks_] = *reinterpret_cast<const bf16x8*>(&Bbuf[bi_][4 + ks_][lane * 8]);  \
    }                                                                               \
    const int code_ = (ct_) * 16 + col;                                             \
    const float cn_ = CnS[code_];                                                   \
    __builtin_amdgcn_s_setprio(1);                                                  \
    _Pragma("unroll")                                                               \
    for (int set_ = 0; set_ < 2; ++set_) {                                          \
      f32x4 aA = (f32x4){0.f,0.f,0.f,0.f};                                          \
      f32x4 aB = (f32x4){0.f,0.f,0.f,0.f};                                          \
      f32x4 aC = (f32x4){0.f,0.f,0.f,0.f};                                          \
      _Pragma("unroll")                                                             \
      for (int ks_ = 0; ks_ < 4; ++ks_) {                                           \
        aA = __builtin_amdgcn_mfma_f32_16x16x32_bf16(ah[set_][ks_], bh_c[ks_], aA, 0,0,0); \
        aB = __builtin_amdgcn_mfma_f32_16x16x32_bf16(ah[set_][ks_], bl_c[ks_], aB, 0,0,0); \
        aC = __builtin_amdgcn_mfma_f32_16x16x32_bf16(al[set_][ks_], bh_c[ks_], aC, 0,0,0); \
      }                                                                             \
      _Pragma("unroll")                                                             \
      for (int reg_ = 0; reg_ < 4; ++reg_) {                                        \
        float S = fmaf(-2.0f, (aA[reg_] + aB[reg_]) + aC[reg_], cn_);               \
        INS4(S, code_, set_, reg_);                                                 \
      }                                                                             \
    }                                                                               \
    __builtin_amdgcn_s_setprio(0); }

#define PHASE(t_, bi_)                                                              \
  { asm volatile("s_waitcnt vmcnt(4)" ::: "memory");                                \
    __builtin_amdgcn_s_barrier();                                                   \
    __builtin_amdgcn_sched_barrier(0);                                              \
    COMP(bi_, t_);                                                                  \
    STAGE(((t_) + 3) & 63, ((bi_) + 3) & 3); }

  __syncthreads();   // CnS visible
  STAGE(0, 0); STAGE(1, 1); STAGE(2, 2);
  for (int g = 0; g < NCT; g += 4) {
    PHASE(g + 0, 0);
    PHASE(g + 1, 1);
    PHASE(g + 2, 2);
    PHASE(g + 3, 3);
  }
#undef PHASE
#undef STAGE
#undef COMP

  // cross-lane (16-col group) top-4 merge: insert other's 4 pairs into mine
#pragma unroll
  for (int m = 1; m < 16; m <<= 1) {
#pragma unroll
    for (int set = 0; set < 2; ++set)
#pragma unroll
      for (int reg = 0; reg < 4; ++reg) {
        float o1 = __shfl_xor(s1v[set][reg], m, 64);
        float o2 = __shfl_xor(s2v[set][reg], m, 64);
        float o3 = __shfl_xor(s3v[set][reg], m, 64);
        float o4 = __shfl_xor(s4v[set][reg], m, 64);
        int   j1 = __shfl_xor(i1v[set][reg], m, 64);
        int   j2 = __shfl_xor(i2v[set][reg], m, 64);
        int   j3 = __shfl_xor(i3v[set][reg], m, 64);
        int   j4 = __shfl_xor(i4v[set][reg], m, 64);
        INS4(o1, j1, set, reg);
        INS4(o2, j2, set, reg);
        INS4(o3, j3, set, reg);
        INS4(o4, j4, set, reg);
      }
  }

  if (col == 0) {
#pragma unroll
    for (int set = 0; set < 2; ++set)
#pragma unroll
      for (int reg = 0; reg < 4; ++reg) {
        int row = wave * 32 + set * 16 + (lane >> 4) * 4 + reg;
        size_t m = (size_t)baseRow + row;
        out_iF[m] = (float)i1v[set][reg];
        gI2[m]    = (float)i2v[set][reg];
        gI3[m]    = (float)i3v[set][reg];
        gG2[m]    = s2v[set][reg] - s1v[set][reg];
        gG4[m]    = s4v[set][reg] - s1v[set][reg];
      }
  }
}

// ---------------- kernel 2: RESOLVE — exact numpy check of <=3 candidates/row --------
__global__ __launch_bounds__(256) void vq_resolve(
    const float* __restrict__ z, const float* __restrict__ cb,
    const float* __restrict__ Cn,
    const float* __restrict__ gI2, const float* __restrict__ gI3,
    const float* __restrict__ gG2, const float* __restrict__ gG4,
    float* __restrict__ out_iF, int* __restrict__ cnt, int* __restrict__ list) {
  const int m = blockIdx.x * 256 + threadIdx.x;
  if (gG2[m] > TAU) return;                 // i1 provably the numpy winner
  if (gG4[m] <= TAU) {                      // rare: >3 candidates -> full-K rescan
    int p = atomicAdd(cnt, 1);
    list[p] = m;
    return;
  }
  // candidates {i1,i2,i3}: exact numpy-fp32 dist (bit-exact R4 recipes)
  const float*  zp  = z + (size_t)m * D;
  const float4* zp4 = reinterpret_cast<const float4*>(zp);
  const float A = np_norm128(zp);
  int cand[3] = {(int)out_iF[m], (int)gI2[m], (int)gI3[m]};
  float bd = 3.402823466e+38f; int bi = 0x7FFFFFFF;
#pragma unroll
  for (int c = 0; c < 3; ++c) {
    int k = cand[c];
    float B = np_dot128(zp4, reinterpret_cast<const float4*>(cb + (size_t)k * D));
    float d = __fadd_rn(__fsub_rn(A, __fmul_rn(2.0f, B)), Cn[k]);
    if (d < bd || (d == bd && k < bi)) { bd = d; bi = k; }
  }
  out_iF[m] = (float)bi;
}

// ---------------- kernel 3: FULL RESCAN — block per listed row (usually 0 rows) ------
__global__ __launch_bounds__(256) void vq_rescan_full(
    const float* __restrict__ z, const float* __restrict__ cb,
    const float* __restrict__ Cn,
    const int* __restrict__ cnt, const int* __restrict__ list,
    float* __restrict__ out_iF) {
  __shared__ float sRed[256];
  __shared__ int   iRed[256];
  const int t = threadIdx.x;
  const int n = *cnt;
  for (int it = blockIdx.x; it < n; it += gridDim.x) {
    const int row = list[it];
    const float*  zp  = z + (size_t)row * D;
    const float4* zp4 = reinterpret_cast<const float4*>(zp);
    const float A = np_norm128(zp);
    const int kb = t * 4;
    float bd = 3.402823466e+38f; int bi = 0;
#pragma unroll
    for (int c = 0; c < 4; ++c) {       // ascending k: strict < keeps first index
      int k = kb + c;
      float B = np_dot128(zp4, reinterpret_cast<const float4*>(cb + (size_t)k * D));
      float d = __fadd_rn(__fsub_rn(A, __fmul_rn(2.0f, B)), Cn[k]);
      if (d < bd) { bd = d; bi = k; }
    }
    sRed[t] = bd; iRed[t] = bi;
    __syncthreads();
    for (int w = 128; w > 0; w >>= 1) {
      if (t < w) {
        float o = sRed[t + w]; int oi = iRed[t + w];
        if (o < sRed[t] || (o == sRed[t] && oi < iRed[t])) { sRed[t] = o; iRed[t] = oi; }
      }
      __syncthreads();
    }
    if (t == 0) out_iF[row] = (float)iRed[0];
    __syncthreads();
  }
}

// ---------------- kernel 4: EPILOGUE — pure-BW gather/STE/loss (validated absmax 0) ---
__global__ __launch_bounds__(256) void vq_epi(
    const float* __restrict__ z, const float* __restrict__ cb,
    const float* __restrict__ out_iF,
    float* __restrict__ out_zq, float* __restrict__ out_q,
    float* __restrict__ out_c) {
  const int t = threadIdx.x;
  const int r = t >> 2, q = t & 3;
  const size_t m = (size_t)blockIdx.x * 64 + r;   // grid 1024
  const int idx = (int)out_iF[m];
  const float4* cq = reinterpret_cast<const float4*>(cb + (size_t)idx * D);
  const float4* zr = reinterpret_cast<const float4*>(z + m * D);
  float4*       o4 = reinterpret_cast<float4*>(out_zq + m * D);
  float sum = 0.f;
#pragma unroll
  for (int e = 0; e < 8; ++e) {
    int d4 = q * 8 + e;
    float4 cv = cq[d4];
    float4 zv = zr[d4];
    float dx = cv.x - zv.x, dy = cv.y - zv.y, dz = cv.z - zv.z, dw = cv.w - zv.w;
    float4 st;
    st.x = zv.x + dx; st.y = zv.y + dy; st.z = zv.z + dz; st.w = zv.w + dw;
    o4[d4] = st;
    sum = fmaf(dx, dx, sum); sum = fmaf(dy, dy, sum);
    sum = fmaf(dz, dz, sum); sum = fmaf(dw, dw, sum);
  }
  sum += __shfl_xor(sum, 1, 64);
  sum += __shfl_xor(sum, 2, 64);
  if (q == 0) {
    float lv = sum * 0.0078125f;   // /128
    out_q[m] = lv;
    out_c[m] = lv;
  }
}

// ---------------- FALLBACK main: R4 kernel verbatim (validated, ~320 us) ---------------
__global__ __launch_bounds__(256) void vq_main_fp32(
    const float* __restrict__ z, const float* __restrict__ cb,
    const float* __restrict__ Cn,
    float* __restrict__ out_zq, float* __restrict__ out_q,
    float* __restrict__ out_c, float* __restrict__ out_i) {
  __shared__ float Zt[64 * D];
  __shared__ float Ct[64 * D];
  __shared__ float Arow[64];
  __shared__ int   idxArr[64];

  const int t  = threadIdx.x;
  const int ty = t >> 4;
  const int tx = t & 15;
  const int baseRow = blockIdx.x * 64;

  for (int s = t; s < 64 * (D / 4); s += 256) {
    int r = s >> 5, d4 = s & 31;
    float4 v = reinterpret_cast<const float4*>(z)[(size_t)(baseRow + r) * (D / 4) + d4];
    int colx = d4 ^ (r & 7);
    *reinterpret_cast<float4*>(&Zt[r * D + colx * 4]) = v;
  }
  __syncthreads();

  if (t < 64) {
    const int rs = t & 7;
    float r8[8];
#pragma unroll
    for (int j = 0; j < 8; ++j) {
      float v = Zt[t * D + (((j >> 2) ^ rs) << 2) + (j & 3)];
      r8[j] = __fmul_rn(v, v);
    }
    for (int i = 8; i < D; i += 8) {
#pragma unroll
      for (int j = 0; j < 8; ++j) {
        int d = i + j;
        float v = Zt[t * D + (((d >> 2) ^ rs) << 2) + (d & 3)];
        r8[j] = __fadd_rn(r8[j], __fmul_rn(v, v));
      }
    }
    Arow[t] = __fadd_rn(__fadd_rn(__fadd_rn(r8[0], r8[1]), __fadd_rn(r8[2], r8[3])),
                        __fadd_rn(__fadd_rn(r8[4], r8[5]), __fadd_rn(r8[6], r8[7])));
  }

  float s1[4]; int i1[4];
#pragma unroll
  for (int i = 0; i < 4; ++i) { s1[i] = 3.402823466e+38f; i1[i] = 0; }

  const int zsw = ty & 7;
  const int csw = tx & 7;

  for (int kt = 0; kt < 16; ++kt) {
    __syncthreads();
    for (int s = t; s < 64 * (D / 4); s += 256) {
      int r = s >> 5, d4 = s & 31;
      float4 v = reinterpret_cast<const float4*>(cb)[(size_t)(kt * 64 + r) * (D / 4) + d4];
      int colx = d4 ^ (r & 7);
      *reinterpret_cast<float4*>(&Ct[r * D + colx * 4]) = v;
    }
    __syncthreads();

    float acc[4][4];
#pragma unroll
    for (int i = 0; i < 4; ++i)
#pragma unroll
      for (int j = 0; j < 4; ++j) acc[i][j] = 0.f;

    for (int d4 = 0; d4 < 32; ++d4) {
      float4 za[4], cv[4];
      int zc = (d4 ^ zsw) * 4;
      int cc = (d4 ^ csw) * 4;
#pragma unroll
      for (int i = 0; i < 4; ++i)
        za[i] = *reinterpret_cast<const float4*>(&Zt[(ty + 16 * i) * D + zc]);
#pragma unroll
      for (int j = 0; j < 4; ++j)
        cv[j] = *reinterpret_cast<const float4*>(&Ct[(tx + 16 * j) * D + cc]);
#pragma unroll
      for (int i = 0; i < 4; ++i)
#pragma unroll
        for (int j = 0; j < 4; ++j) {
          acc[i][j] = fmaf(za[i].x, cv[j].x, acc[i][j]);
          acc[i][j] = fmaf(za[i].y, cv[j].y, acc[i][j]);
          acc[i][j] = fmaf(za[i].z, cv[j].z, acc[i][j]);
          acc[i][j] = fmaf(za[i].w, cv[j].w, acc[i][j]);
        }
    }

    float ch[4]; int kg[4];
#pragma unroll
    for (int j = 0; j < 4; ++j) {
      kg[j] = kt * 64 + tx + 16 * j;
      ch[j] = Cn[kg[j]];
    }
#pragma unroll
    for (int i = 0; i < 4; ++i) {
      float a = Arow[ty + 16 * i];
#pragma unroll
      for (int j = 0; j < 4; ++j) {
        float dist = __fadd_rn(__fsub_rn(a, __fmul_rn(2.0f, acc[i][j])), ch[j]);
        if (dist < s1[i]) { s1[i] = dist; i1[i] = kg[j]; }
      }
    }
  }

#pragma unroll
  for (int m = 1; m < 16; m <<= 1) {
#pragma unroll
    for (int i = 0; i < 4; ++i) {
      float os = __shfl_xor(s1[i], m, 64);
      int   oi = __shfl_xor(i1[i], m, 64);
      if (os < s1[i] || (os == s1[i] && oi < i1[i])) { s1[i] = os; i1[i] = oi; }
    }
  }

  if (tx == 0) {
#pragma unroll
    for (int i = 0; i < 4; ++i) idxArr[ty + 16 * i] = i1[i];
  }
  __syncthreads();

  {
    int r = t >> 2, q = t & 3;
    int idx = idxArr[r];
    size_t m = (size_t)baseRow + r;
    const float4* cq = reinterpret_cast<const float4*>(cb + (size_t)idx * D);
    const float4* zr = reinterpret_cast<const float4*>(z + m * D);
    float4*       o4 = reinterpret_cast<float4*>(out_zq + m * D);
    float sum = 0.f;
#pragma unroll
    for (int e = 0; e < 8; ++e) {
      int d4 = q * 8 + e;
      float4 cv = cq[d4];
      float4 zv = zr[d4];
      float dx = cv.x - zv.x, dy = cv.y - zv.y, dz = cv.z - zv.z, dw = cv.w - zv.w;
      float4 st;
      st.x = zv.x + dx; st.y = zv.y + dy; st.z = zv.z + dz; st.w = zv.w + dw;
      o4[d4] = st;
      sum = fmaf(dx, dx, sum); sum = fmaf(dy, dy, sum);
      sum = fmaf(dz, dz, sum); sum = fmaf(dw, dw, sum);
    }
    sum += __shfl_xor(sum, 1, 64);
    sum += __shfl_xor(sum, 2, 64);
    if (q == 0) {
      float lv = sum * 0.0078125f;
      out_q[m] = lv;
      out_c[m] = lv;
      out_i[m] = (float)idx;
    }
  }
}

extern "C" void kernel_launch(void* const* d_in, const int* in_sizes, int n_in,
                              void* d_out, int out_size, void* d_ws, size_t ws_size,
                              hipStream_t stream) {
  const float* z  = (const float*)d_in[0];   // [16,4096,128] fp32
  const float* cb = (const float*)d_in[1];   // [1024,128] fp32

  float* out0 = (float*)d_out;               // z_q_ste  [M,128]
  float* out1 = out0 + (size_t)M_TOTAL * D;  // quant_loss [M]
  float* out2 = out1 + M_TOTAL;              // commit_loss [M]
  float* out3 = out2 + M_TOTAL;              // indices (as float) [M]

  float* Cn = (float*)((char*)d_ws + WS_CN);
  // scratch: candidate info in out0 (overwritten by epi), rescan list in out2
  float* gI2  = out0;
  float* gI3  = out0 + M_TOTAL;
  float* gG2  = out0 + 2 * M_TOTAL;
  float* gG4  = out0 + 3 * M_TOTAL;
  int*   cnt  = (int*)out2;
  int*   list = (int*)out2 + 1;

  vq_prep<<<(K + 255) / 256, 256, 0, stream>>>(cb, Cn, cnt);

  if (ws_size >= WS_REQ) {
    short* Bh = (short*)((char*)d_ws + WS_BH);
    short* Bl = (short*)((char*)d_ws + WS_BL);
    vq_frag<<<64, 256, 0, stream>>>(cb, Bh, Bl);
    vq_score<<<M_TOTAL / BM, 256, 0, stream>>>(z, Cn, Bh, Bl, out3, gI2, gI3, gG2, gG4);
    vq_resolve<<<M_TOTAL / 256, 256, 0, stream>>>(z, cb, Cn, gI2, gI3, gG2, gG4,
                                                  out3, cnt, list);
    vq_rescan_full<<<16, 256, 0, stream>>>(z, cb, Cn, cnt, list, out3);
    vq_epi<<<M_TOTAL / 64, 256, 0, stream>>>(z, cb, out3, out0, out1, out2);
  } else {
    vq_main_fp32<<<M_TOTAL / 64, 256, 0, stream>>>(z, cb, Cn, out0, out1, out2, out3);
  }
}

// Round 18
// 190.060 us; speedup vs baseline: 1.5051x; 1.3543x over previous
//
#include <hip/hip_runtime.h>
#include <hip/hip_bf16.h>

namespace {
constexpr int D       = 128;
constexpr int K       = 1024;
constexpr int M_TOTAL = 65536;   // 16 * 4096
constexpr int BM      = 128;     // rows per score-block: 4 waves x 32 rows
constexpr int NCT     = K / 16;  // 64 code-tiles of 16 codes
constexpr float TAU   = 5.0e-5f; // > 2*(scorer err) + 2*(numpy quantization span)
// d_ws layout
constexpr size_t WS_CN  = 0;                 // float[1024]         (4 KB)
constexpr size_t WS_BH  = 4096;              // short[131072]       (256 KB)
constexpr size_t WS_BL  = 4096 + 262144;     // short[131072]       (256 KB)
constexpr size_t WS_REQ = 4096 + 2 * 262144; // 528,384 B (confirmed available, R11-R17)
}

typedef short bf16x8 __attribute__((ext_vector_type(8)));
typedef float f32x4  __attribute__((ext_vector_type(4)));

static __device__ __forceinline__ unsigned short bfbits(float x) {
  __hip_bfloat16 h = __float2bfloat16(x);   // RNE
  return *reinterpret_cast<unsigned short*>(&h);
}
static __device__ __forceinline__ float bfhi2f(unsigned short h) {
  return __uint_as_float(((unsigned)h) << 16);
}
static __device__ __forceinline__ void split8(float4 a, float4 b,
                                              bf16x8& ph, bf16x8& pl) {
  float v[8] = {a.x, a.y, a.z, a.w, b.x, b.y, b.z, b.w};
#pragma unroll
  for (int e = 0; e < 8; ++e) {
    unsigned short h = bfbits(v[e]);
    unsigned short l = bfbits(v[e] - bfhi2f(h));
    ph[e] = (short)h;
    pl[e] = (short)l;
  }
}
// numpy pairwise-8 row norm of 128 consecutive floats (R4-validated, bit-exact)
static __device__ __forceinline__ float np_norm128(const float* p) {
  float r8[8];
#pragma unroll
  for (int j = 0; j < 8; ++j) r8[j] = __fmul_rn(p[j], p[j]);
  for (int i = 8; i < D; i += 8) {
#pragma unroll
    for (int j = 0; j < 8; ++j)
      r8[j] = __fadd_rn(r8[j], __fmul_rn(p[i + j], p[i + j]));
  }
  return __fadd_rn(__fadd_rn(__fadd_rn(r8[0], r8[1]), __fadd_rn(r8[2], r8[3])),
                   __fadd_rn(__fadd_rn(r8[4], r8[5]), __fadd_rn(r8[6], r8[7])));
}

// ---------------- prep 1: Cn + zero rescan counter ----------------
__global__ void vq_prep(const float* __restrict__ cb, float* __restrict__ Cn,
                        int* __restrict__ cnt) {
  int k = blockIdx.x * 256 + threadIdx.x;
  if (k == 0) *cnt = 0;
  if (k >= K) return;
  Cn[k] = np_norm128(cb + (size_t)k * D);
}

// ---------------- prep 2: codebook -> hi/lo bf16 planes, fragment-linear (validated) ----
__global__ void vq_frag(const float* __restrict__ cb,
                        short* __restrict__ Bh, short* __restrict__ Bl) {
  int g = blockIdx.x * 256 + threadIdx.x;           // 0 .. 16383
  int code = (g >> 8) * 16 + (g & 15);
  int d0   = ((g >> 6) & 3) * 32 + ((g >> 4) & 3) * 8;
  const float* p = cb + (size_t)code * D + d0;
  float4 a = *reinterpret_cast<const float4*>(p);
  float4 b = *reinterpret_cast<const float4*>(p + 4);
  bf16x8 ph, pl;
  split8(a, b, ph, pl);
  *reinterpret_cast<bf16x8*>(Bh + (size_t)g * 8) = ph;
  *reinterpret_cast<bf16x8*>(Bl + (size_t)g * 8) = pl;
}

// ---------------- kernel 1: SCORE — R16-proven top-2 pipeline (66 us, absmax 0) -------
__global__ __launch_bounds__(256, 2) void vq_score(
    const float* __restrict__ z, const float* __restrict__ Cn,
    const short* __restrict__ BhG, const short* __restrict__ BlG,
    float* __restrict__ out_iF, float* __restrict__ out_gap) {
  __shared__ __align__(16) short Bbuf[4][8][512];   // 32 KB
  __shared__ float CnS[K];                           // 4 KB

  const int t    = threadIdx.x;
  const int wave = t >> 6;
  const int lane = t & 63;
  const int col  = lane & 15;
  const int baseRow = blockIdx.x * BM;

  for (int i = t; i < K; i += 256) CnS[i] = Cn[i];

  bf16x8 ah[2][4], al[2][4];
#pragma unroll
  for (int set = 0; set < 2; ++set) {
    const float* zL = z + (size_t)(baseRow + wave * 32 + set * 16 + col) * D + (lane >> 4) * 8;
#pragma unroll
    for (int ks = 0; ks < 4; ++ks) {
      float4 a = *reinterpret_cast<const float4*>(zL + ks * 32);
      float4 b = *reinterpret_cast<const float4*>(zL + ks * 32 + 4);
      split8(a, b, ah[set][ks], al[set][ks]);
    }
  }

  float s1[2][4], s2[2][4]; int i1[2][4];
#pragma unroll
  for (int s = 0; s < 2; ++s)
#pragma unroll
    for (int i = 0; i < 4; ++i) {
      s1[s][i] = 3.402823466e+38f; s2[s][i] = 3.402823466e+38f; i1[s][i] = 0;
    }

#define STAGE(ct_, bi_)                                                             \
  { _Pragma("unroll")                                                               \
    for (int i_ = 0; i_ < 2; ++i_) {                                                \
      int c_  = wave * 2 + i_;                                                      \
      int p_  = c_ >> 2, ks_ = c_ & 3;                                              \
      const short* gsrc_ = (p_ ? BlG : BhG) +                                       \
                           (size_t)(((ct_) * 4 + ks_) * 64 + lane) * 8;             \
      __builtin_amdgcn_global_load_lds(                                             \
          (const __attribute__((address_space(1))) void*)gsrc_,                     \
          (__attribute__((address_space(3))) void*)&Bbuf[bi_][c_][0], 16, 0, 0);    \
    } }

#define COMP(bi_, ct_)                                                              \
  { bf16x8 bh_c[4], bl_c[4];                                                        \
    _Pragma("unroll")                                                               \
    for (int ks_ = 0; ks_ < 4; ++ks_) {                                             \
      bh_c[ks_] = *reinterpret_cast<const bf16x8*>(&Bbuf[bi_][ks_][lane * 8]);      \
      bl_c[ks_] = *reinterpret_cast<const bf16x8*>(&Bbuf[bi_][4 + ks_][lane * 8]);  \
    }                                                                               \
    const int code_ = (ct_) * 16 + col;                                             \
    const float cn_ = CnS[code_];                                                   \
    __builtin_amdgcn_s_setprio(1);                                                  \
    _Pragma("unroll")                                                               \
    for (int set_ = 0; set_ < 2; ++set_) {                                          \
      f32x4 aA = (f32x4){0.f,0.f,0.f,0.f};                                          \
      f32x4 aB = (f32x4){0.f,0.f,0.f,0.f};                                          \
      f32x4 aC = (f32x4){0.f,0.f,0.f,0.f};                                          \
      _Pragma("unroll")                                                             \
      for (int ks_ = 0; ks_ < 4; ++ks_) {                                           \
        aA = __builtin_amdgcn_mfma_f32_16x16x32_bf16(ah[set_][ks_], bh_c[ks_], aA, 0,0,0); \
        aB = __builtin_amdgcn_mfma_f32_16x16x32_bf16(ah[set_][ks_], bl_c[ks_], aB, 0,0,0); \
        aC = __builtin_amdgcn_mfma_f32_16x16x32_bf16(al[set_][ks_], bh_c[ks_], aC, 0,0,0); \
      }                                                                             \
      _Pragma("unroll")                                                             \
      for (int reg_ = 0; reg_ < 4; ++reg_) {                                        \
        float S = fmaf(-2.0f, (aA[reg_] + aB[reg_]) + aC[reg_], cn_);               \
        if (S < s1[set_][reg_]) { s2[set_][reg_] = s1[set_][reg_];                  \
                                  s1[set_][reg_] = S; i1[set_][reg_] = code_; }     \
        else if (S < s2[set_][reg_]) { s2[set_][reg_] = S; }                        \
      }                                                                             \
    }                                                                               \
    __builtin_amdgcn_s_setprio(0); }

#define PHASE(t_, bi_)                                                              \
  { asm volatile("s_waitcnt vmcnt(4)" ::: "memory");                                \
    __builtin_amdgcn_s_barrier();                                                   \
    __builtin_amdgcn_sched_barrier(0);                                              \
    COMP(bi_, t_);                                                                  \
    STAGE(((t_) + 3) & 63, ((bi_) + 3) & 3); }

  __syncthreads();   // CnS visible
  STAGE(0, 0); STAGE(1, 1); STAGE(2, 2);
  for (int g = 0; g < NCT; g += 4) {
    PHASE(g + 0, 0);
    PHASE(g + 1, 1);
    PHASE(g + 2, 2);
    PHASE(g + 3, 3);
  }
#undef PHASE
#undef STAGE
#undef COMP

  // cross-lane (16-col group) min1/min2 merge
#pragma unroll
  for (int m = 1; m < 16; m <<= 1) {
#pragma unroll
    for (int set = 0; set < 2; ++set)
#pragma unroll
      for (int reg = 0; reg < 4; ++reg) {
        float os1 = __shfl_xor(s1[set][reg], m, 64);
        float os2 = __shfl_xor(s2[set][reg], m, 64);
        int   oi  = __shfl_xor(i1[set][reg], m, 64);
        if (os1 < s1[set][reg]) {
          s2[set][reg] = fminf(s1[set][reg], os2);
          s1[set][reg] = os1; i1[set][reg] = oi;
        } else {
          s2[set][reg] = fminf(s2[set][reg], os1);
        }
      }
  }

  if (col == 0) {
#pragma unroll
    for (int set = 0; set < 2; ++set)
#pragma unroll
      for (int reg = 0; reg < 4; ++reg) {
        int row = wave * 32 + set * 16 + (lane >> 4) * 4 + reg;
        size_t m = (size_t)baseRow + row;
        out_iF[m]  = (float)i1[set][reg];
        out_gap[m] = s2[set][reg] - s1[set][reg];
      }
  }
}

// ---------------- kernel 2: COLLECT — build global hard-row list ----------------
__global__ __launch_bounds__(256) void vq_collect(
    const float* __restrict__ gap, int* __restrict__ cnt, int* __restrict__ list) {
  const int m = blockIdx.x * 256 + threadIdx.x;
  if (gap[m] < TAU) {
    int p = atomicAdd(cnt, 1);
    if (p < M_TOTAL - 1) list[p] = m;
  }
}

// ---------------- kernel 3: FULL RESCAN — block per hard row, 4 interleaved chains ----
__global__ __launch_bounds__(256, 4) void vq_rescan_full(
    const float* __restrict__ z, const float* __restrict__ cb,
    const float* __restrict__ Cn,
    const int* __restrict__ cnt, const int* __restrict__ list,
    float* __restrict__ out_iF) {
  __shared__ __align__(16) float Zs[D];
  __shared__ float sRed[256];
  __shared__ int   iRed[256];
  const int t = threadIdx.x;
  int n = *cnt; if (n > M_TOTAL - 1) n = M_TOTAL - 1;

  for (int it = blockIdx.x; it < n; it += gridDim.x) {
    const int row = list[it];
    if (t < 32) {
      reinterpret_cast<float4*>(Zs)[t] =
          reinterpret_cast<const float4*>(z + (size_t)row * D)[t];
    }
    __syncthreads();

    const float4* zp4 = reinterpret_cast<const float4*>(Zs);
    const int kb = t * 4;
    const float4* c0 = reinterpret_cast<const float4*>(cb + (size_t)(kb + 0) * D);
    const float4* c1 = reinterpret_cast<const float4*>(cb + (size_t)(kb + 1) * D);
    const float4* c2 = reinterpret_cast<const float4*>(cb + (size_t)(kb + 2) * D);
    const float4* c3 = reinterpret_cast<const float4*>(cb + (size_t)(kb + 3) * D);
    // 4 exact sequential-FMA dot chains (ascending d) + numpy pairwise-8 norm folded in.
    float a0 = 0.f, a1 = 0.f, a2 = 0.f, a3 = 0.f;
    float r8[8];
#pragma unroll
    for (int j = 0; j < 8; ++j) r8[j] = 0.f;   // fadd(0,x^2)==x^2 exact
#pragma unroll 8
    for (int d4 = 0; d4 < 32; ++d4) {
      float4 zv = zp4[d4];                     // LDS broadcast
      float4 v0 = c0[d4], v1 = c1[d4], v2 = c2[d4], v3 = c3[d4];
      a0 = fmaf(zv.x, v0.x, a0); a0 = fmaf(zv.y, v0.y, a0);
      a0 = fmaf(zv.z, v0.z, a0); a0 = fmaf(zv.w, v0.w, a0);
      a1 = fmaf(zv.x, v1.x, a1); a1 = fmaf(zv.y, v1.y, a1);
      a1 = fmaf(zv.z, v1.z, a1); a1 = fmaf(zv.w, v1.w, a1);
      a2 = fmaf(zv.x, v2.x, a2); a2 = fmaf(zv.y, v2.y, a2);
      a2 = fmaf(zv.z, v2.z, a2); a2 = fmaf(zv.w, v2.w, a2);
      a3 = fmaf(zv.x, v3.x, a3); a3 = fmaf(zv.y, v3.y, a3);
      a3 = fmaf(zv.z, v3.z, a3); a3 = fmaf(zv.w, v3.w, a3);
      // norm: d = 4*d4+e -> j = d&7 (even d4: e, odd d4: 4+e); d ascending per j ✓
      const int jb = (d4 & 1) * 4;
      r8[jb + 0] = __fadd_rn(r8[jb + 0], __fmul_rn(zv.x, zv.x));
      r8[jb + 1] = __fadd_rn(r8[jb + 1], __fmul_rn(zv.y, zv.y));
      r8[jb + 2] = __fadd_rn(r8[jb + 2], __fmul_rn(zv.z, zv.z));
      r8[jb + 3] = __fadd_rn(r8[jb + 3], __fmul_rn(zv.w, zv.w));
    }
    const float A =
        __fadd_rn(__fadd_rn(__fadd_rn(r8[0], r8[1]), __fadd_rn(r8[2], r8[3])),
                  __fadd_rn(__fadd_rn(r8[4], r8[5]), __fadd_rn(r8[6], r8[7])));

    float bd = 3.402823466e+38f; int bi = 0;
    {  // ascending k, strict <: numpy first-occurrence
      float d0 = __fadd_rn(__fsub_rn(A, __fmul_rn(2.0f, a0)), Cn[kb + 0]);
      float d1 = __fadd_rn(__fsub_rn(A, __fmul_rn(2.0f, a1)), Cn[kb + 1]);
      float d2 = __fadd_rn(__fsub_rn(A, __fmul_rn(2.0f, a2)), Cn[kb + 2]);
      float d3 = __fadd_rn(__fsub_rn(A, __fmul_rn(2.0f, a3)), Cn[kb + 3]);
      if (d0 < bd) { bd = d0; bi = kb + 0; }
      if (d1 < bd) { bd = d1; bi = kb + 1; }
      if (d2 < bd) { bd = d2; bi = kb + 2; }
      if (d3 < bd) { bd = d3; bi = kb + 3; }
    }
    sRed[t] = bd; iRed[t] = bi;
    __syncthreads();
    for (int w = 128; w > 0; w >>= 1) {
      if (t < w) {
        float o = sRed[t + w]; int oi = iRed[t + w];
        if (o < sRed[t] || (o == sRed[t] && oi < iRed[t])) { sRed[t] = o; iRed[t] = oi; }
      }
      __syncthreads();
    }
    if (t == 0) out_iF[row] = (float)iRed[0];
    __syncthreads();   // protect Zs before next iteration
  }
}

// ---------------- kernel 4: EPILOGUE — pure-BW gather/STE/loss (validated absmax 0) ---
__global__ __launch_bounds__(256) void vq_epi(
    const float* __restrict__ z, const float* __restrict__ cb,
    const float* __restrict__ out_iF,
    float* __restrict__ out_zq, float* __restrict__ out_q,
    float* __restrict__ out_c) {
  const int t = threadIdx.x;
  const int r = t >> 2, q = t & 3;
  const size_t m = (size_t)blockIdx.x * 64 + r;   // grid 1024
  const int idx = (int)out_iF[m];
  const float4* cq = reinterpret_cast<const float4*>(cb + (size_t)idx * D);
  const float4* zr = reinterpret_cast<const float4*>(z + m * D);
  float4*       o4 = reinterpret_cast<float4*>(out_zq + m * D);
  float sum = 0.f;
#pragma unroll
  for (int e = 0; e < 8; ++e) {
    int d4 = q * 8 + e;
    float4 cv = cq[d4];
    float4 zv = zr[d4];
    float dx = cv.x - zv.x, dy = cv.y - zv.y, dz = cv.z - zv.z, dw = cv.w - zv.w;
    float4 st;
    st.x = zv.x + dx; st.y = zv.y + dy; st.z = zv.z + dz; st.w = zv.w + dw;
    o4[d4] = st;
    sum = fmaf(dx, dx, sum); sum = fmaf(dy, dy, sum);
    sum = fmaf(dz, dz, sum); sum = fmaf(dw, dw, sum);
  }
  sum += __shfl_xor(sum, 1, 64);
  sum += __shfl_xor(sum, 2, 64);
  if (q == 0) {
    float lv = sum * 0.0078125f;   // /128
    out_q[m] = lv;
    out_c[m] = lv;
  }
}

// ---------------- FALLBACK main: R4 kernel verbatim (validated, ~320 us) ---------------
__global__ __launch_bounds__(256) void vq_main_fp32(
    const float* __restrict__ z, const float* __restrict__ cb,
    const float* __restrict__ Cn,
    float* __restrict__ out_zq, float* __restrict__ out_q,
    float* __restrict__ out_c, float* __restrict__ out_i) {
  __shared__ float Zt[64 * D];
  __shared__ float Ct[64 * D];
  __shared__ float Arow[64];
  __shared__ int   idxArr[64];

  const int t  = threadIdx.x;
  const int ty = t >> 4;
  const int tx = t & 15;
  const int baseRow = blockIdx.x * 64;

  for (int s = t; s < 64 * (D / 4); s += 256) {
    int r = s >> 5, d4 = s & 31;
    float4 v = reinterpret_cast<const float4*>(z)[(size_t)(baseRow + r) * (D / 4) + d4];
    int colx = d4 ^ (r & 7);
    *reinterpret_cast<float4*>(&Zt[r * D + colx * 4]) = v;
  }
  __syncthreads();

  if (t < 64) {
    const int rs = t & 7;
    float r8[8];
#pragma unroll
    for (int j = 0; j < 8; ++j) {
      float v = Zt[t * D + (((j >> 2) ^ rs) << 2) + (j & 3)];
      r8[j] = __fmul_rn(v, v);
    }
    for (int i = 8; i < D; i += 8) {
#pragma unroll
      for (int j = 0; j < 8; ++j) {
        int d = i + j;
        float v = Zt[t * D + (((d >> 2) ^ rs) << 2) + (d & 3)];
        r8[j] = __fadd_rn(r8[j], __fmul_rn(v, v));
      }
    }
    Arow[t] = __fadd_rn(__fadd_rn(__fadd_rn(r8[0], r8[1]), __fadd_rn(r8[2], r8[3])),
                        __fadd_rn(__fadd_rn(r8[4], r8[5]), __fadd_rn(r8[6], r8[7])));
  }

  float s1[4]; int i1[4];
#pragma unroll
  for (int i = 0; i < 4; ++i) { s1[i] = 3.402823466e+38f; i1[i] = 0; }

  const int zsw = ty & 7;
  const int csw = tx & 7;

  for (int kt = 0; kt < 16; ++kt) {
    __syncthreads();
    for (int s = t; s < 64 * (D / 4); s += 256) {
      int r = s >> 5, d4 = s & 31;
      float4 v = reinterpret_cast<const float4*>(cb)[(size_t)(kt * 64 + r) * (D / 4) + d4];
      int colx = d4 ^ (r & 7);
      *reinterpret_cast<float4*>(&Ct[r * D + colx * 4]) = v;
    }
    __syncthreads();

    float acc[4][4];
#pragma unroll
    for (int i = 0; i < 4; ++i)
#pragma unroll
      for (int j = 0; j < 4; ++j) acc[i][j] = 0.f;

    for (int d4 = 0; d4 < 32; ++d4) {
      float4 za[4], cv[4];
      int zc = (d4 ^ zsw) * 4;
      int cc = (d4 ^ csw) * 4;
#pragma unroll
      for (int i = 0; i < 4; ++i)
        za[i] = *reinterpret_cast<const float4*>(&Zt[(ty + 16 * i) * D + zc]);
#pragma unroll
      for (int j = 0; j < 4; ++j)
        cv[j] = *reinterpret_cast<const float4*>(&Ct[(tx + 16 * j) * D + cc]);
#pragma unroll
      for (int i = 0; i < 4; ++i)
#pragma unroll
        for (int j = 0; j < 4; ++j) {
          acc[i][j] = fmaf(za[i].x, cv[j].x, acc[i][j]);
          acc[i][j] = fmaf(za[i].y, cv[j].y, acc[i][j]);
          acc[i][j] = fmaf(za[i].z, cv[j].z, acc[i][j]);
          acc[i][j] = fmaf(za[i].w, cv[j].w, acc[i][j]);
        }
    }

    float ch[4]; int kg[4];
#pragma unroll
    for (int j = 0; j < 4; ++j) {
      kg[j] = kt * 64 + tx + 16 * j;
      ch[j] = Cn[kg[j]];
    }
#pragma unroll
    for (int i = 0; i < 4; ++i) {
      float a = Arow[ty + 16 * i];
#pragma unroll
      for (int j = 0; j < 4; ++j) {
        float dist = __fadd_rn(__fsub_rn(a, __fmul_rn(2.0f, acc[i][j])), ch[j]);
        if (dist < s1[i]) { s1[i] = dist; i1[i] = kg[j]; }
      }
    }
  }

#pragma unroll
  for (int m = 1; m < 16; m <<= 1) {
#pragma unroll
    for (int i = 0; i < 4; ++i) {
      float os = __shfl_xor(s1[i], m, 64);
      int   oi = __shfl_xor(i1[i], m, 64);
      if (os < s1[i] || (os == s1[i] && oi < i1[i])) { s1[i] = os; i1[i] = oi; }
    }
  }

  if (tx == 0) {
#pragma unroll
    for (int i = 0; i < 4; ++i) idxArr[ty + 16 * i] = i1[i];
  }
  __syncthreads();

  {
    int r = t >> 2, q = t & 3;
    int idx = idxArr[r];
    size_t m = (size_t)baseRow + r;
    const float4* cq = reinterpret_cast<const float4*>(cb + (size_t)idx * D);
    const float4* zr = reinterpret_cast<const float4*>(z + m * D);
    float4*       o4 = reinterpret_cast<float4*>(out_zq + m * D);
    float sum = 0.f;
#pragma unroll
    for (int e = 0; e < 8; ++e) {
      int d4 = q * 8 + e;
      float4 cv = cq[d4];
      float4 zv = zr[d4];
      float dx = cv.x - zv.x, dy = cv.y - zv.y, dz = cv.z - zv.z, dw = cv.w - zv.w;
      float4 st;
      st.x = zv.x + dx; st.y = zv.y + dy; st.z = zv.z + dz; st.w = zv.w + dw;
      o4[d4] = st;
      sum = fmaf(dx, dx, sum); sum = fmaf(dy, dy, sum);
      sum = fmaf(dz, dz, sum); sum = fmaf(dw, dw, sum);
    }
    sum += __shfl_xor(sum, 1, 64);
    sum += __shfl_xor(sum, 2, 64);
    if (q == 0) {
      float lv = sum * 0.0078125f;
      out_q[m] = lv;
      out_c[m] = lv;
      out_i[m] = (float)idx;
    }
  }
}

extern "C" void kernel_launch(void* const* d_in, const int* in_sizes, int n_in,
                              void* d_out, int out_size, void* d_ws, size_t ws_size,
                              hipStream_t stream) {
  const float* z  = (const float*)d_in[0];   // [16,4096,128] fp32
  const float* cb = (const float*)d_in[1];   // [1024,128] fp32

  float* out0 = (float*)d_out;               // z_q_ste  [M,128]
  float* out1 = out0 + (size_t)M_TOTAL * D;  // quant_loss [M]
  float* out2 = out1 + M_TOTAL;              // commit_loss [M]
  float* out3 = out2 + M_TOTAL;              // indices (as float) [M]

  float* Cn = (float*)((char*)d_ws + WS_CN);
  // scratch: gap in out1, cnt+list in out2 (both overwritten by epi)
  int* cnt  = (int*)out2;
  int* list = (int*)out2 + 1;

  vq_prep<<<(K + 255) / 256, 256, 0, stream>>>(cb, Cn, cnt);

  if (ws_size >= WS_REQ) {
    short* Bh = (short*)((char*)d_ws + WS_BH);
    short* Bl = (short*)((char*)d_ws + WS_BL);
    vq_frag<<<64, 256, 0, stream>>>(cb, Bh, Bl);
    vq_score<<<M_TOTAL / BM, 256, 0, stream>>>(z, Cn, Bh, Bl, out3, out1);
    vq_collect<<<M_TOTAL / 256, 256, 0, stream>>>(out1, cnt, list);
    vq_rescan_full<<<1024, 256, 0, stream>>>(z, cb, Cn, cnt, list, out3);
    vq_epi<<<M_TOTAL / 64, 256, 0, stream>>>(z, cb, out3, out0, out1, out2);
  } else {
    vq_main_fp32<<<M_TOTAL / 64, 256, 0, stream>>>(z, cb, Cn, out0, out1, out2, out3);
  }
}

// Round 19
// 123.696 us; speedup vs baseline: 2.3126x; 1.5365x over previous
//
#include <hip/hip_runtime.h>
#include <hip/hip_bf16.h>

namespace {
constexpr int D       = 128;
constexpr int K       = 1024;
constexpr int M_TOTAL = 65536;   // 16 * 4096
constexpr int BM      = 128;     // rows per score-block: 4 waves x 32 rows
constexpr int NCT     = K / 16;  // 64 code-tiles of 16 codes
constexpr float TAU   = 5.0e-5f; // > 2*(scorer err) + 2*(numpy quantization span)
// d_ws layout
constexpr size_t WS_CN   = 0;                    // float[1024]     (4 KB)
constexpr size_t WS_BH   = 4096;                 // short[131072]   (256 KB)
constexpr size_t WS_BL   = 4096 + 262144;        // short[131072]   (256 KB)
constexpr size_t WS_REQ  = 4096 + 2 * 262144;    // 528,384 B (confirmed, R11-R18)
constexpr size_t WS_CBT  = WS_REQ;               // float4[32768]   (512 KB)
constexpr size_t WS_REQ2 = WS_REQ + 524288;      // 1,052,672 B (probing this round)
}

typedef short bf16x8 __attribute__((ext_vector_type(8)));
typedef float f32x4  __attribute__((ext_vector_type(4)));

static __device__ __forceinline__ unsigned short bfbits(float x) {
  __hip_bfloat16 h = __float2bfloat16(x);   // RNE
  return *reinterpret_cast<unsigned short*>(&h);
}
static __device__ __forceinline__ float bfhi2f(unsigned short h) {
  return __uint_as_float(((unsigned)h) << 16);
}
static __device__ __forceinline__ void split8(float4 a, float4 b,
                                              bf16x8& ph, bf16x8& pl) {
  float v[8] = {a.x, a.y, a.z, a.w, b.x, b.y, b.z, b.w};
#pragma unroll
  for (int e = 0; e < 8; ++e) {
    unsigned short h = bfbits(v[e]);
    unsigned short l = bfbits(v[e] - bfhi2f(h));
    ph[e] = (short)h;
    pl[e] = (short)l;
  }
}
// numpy pairwise-8 row norm of 128 consecutive floats (R4-validated, bit-exact)
static __device__ __forceinline__ float np_norm128(const float* p) {
  float r8[8];
#pragma unroll
  for (int j = 0; j < 8; ++j) r8[j] = __fmul_rn(p[j], p[j]);
  for (int i = 8; i < D; i += 8) {
#pragma unroll
    for (int j = 0; j < 8; ++j)
      r8[j] = __fadd_rn(r8[j], __fmul_rn(p[i + j], p[i + j]));
  }
  return __fadd_rn(__fadd_rn(__fadd_rn(r8[0], r8[1]), __fadd_rn(r8[2], r8[3])),
                   __fadd_rn(__fadd_rn(r8[4], r8[5]), __fadd_rn(r8[6], r8[7])));
}

// ---------------- prep 1: Cn + zero rescan counter ----------------
__global__ void vq_prep(const float* __restrict__ cb, float* __restrict__ Cn,
                        int* __restrict__ cnt) {
  int k = blockIdx.x * 256 + threadIdx.x;
  if (k == 0) *cnt = 0;
  if (k >= K) return;
  Cn[k] = np_norm128(cb + (size_t)k * D);
}

// ---------------- prep 2: codebook -> hi/lo bf16 planes, fragment-linear (validated) ----
__global__ void vq_frag(const float* __restrict__ cb,
                        short* __restrict__ Bh, short* __restrict__ Bl) {
  int g = blockIdx.x * 256 + threadIdx.x;           // 0 .. 16383
  int code = (g >> 8) * 16 + (g & 15);
  int d0   = ((g >> 6) & 3) * 32 + ((g >> 4) & 3) * 8;
  const float* p = cb + (size_t)code * D + d0;
  float4 a = *reinterpret_cast<const float4*>(p);
  float4 b = *reinterpret_cast<const float4*>(p + 4);
  bf16x8 ph, pl;
  split8(a, b, ph, pl);
  *reinterpret_cast<bf16x8*>(Bh + (size_t)g * 8) = ph;
  *reinterpret_cast<bf16x8*>(Bl + (size_t)g * 8) = pl;
}

// ---------------- prep 3: transposed codebook cbT4[(d<<8)+t] = cb[4t..4t+3][d] --------
// one-time; reads L2-resident cb (scattered ok), writes coalesced-enough. 512 KB.
__global__ void vq_trans(const float* __restrict__ cb, float4* __restrict__ cbT4) {
  int g = blockIdx.x * 256 + threadIdx.x;   // 0 .. 32767
  int d = g >> 8, t = g & 255;
  float4 v;
  v.x = cb[(size_t)(4 * t + 0) * D + d];
  v.y = cb[(size_t)(4 * t + 1) * D + d];
  v.z = cb[(size_t)(4 * t + 2) * D + d];
  v.w = cb[(size_t)(4 * t + 3) * D + d];
  cbT4[g] = v;
}

// ---------------- kernel 1: SCORE — R16-proven top-2 pipeline (absmax 0) -------
__global__ __launch_bounds__(256, 2) void vq_score(
    const float* __restrict__ z, const float* __restrict__ Cn,
    const short* __restrict__ BhG, const short* __restrict__ BlG,
    float* __restrict__ out_iF, float* __restrict__ out_gap) {
  __shared__ __align__(16) short Bbuf[4][8][512];   // 32 KB
  __shared__ float CnS[K];                           // 4 KB

  const int t    = threadIdx.x;
  const int wave = t >> 6;
  const int lane = t & 63;
  const int col  = lane & 15;
  const int baseRow = blockIdx.x * BM;

  for (int i = t; i < K; i += 256) CnS[i] = Cn[i];

  bf16x8 ah[2][4], al[2][4];
#pragma unroll
  for (int set = 0; set < 2; ++set) {
    const float* zL = z + (size_t)(baseRow + wave * 32 + set * 16 + col) * D + (lane >> 4) * 8;
#pragma unroll
    for (int ks = 0; ks < 4; ++ks) {
      float4 a = *reinterpret_cast<const float4*>(zL + ks * 32);
      float4 b = *reinterpret_cast<const float4*>(zL + ks * 32 + 4);
      split8(a, b, ah[set][ks], al[set][ks]);
    }
  }

  float s1[2][4], s2[2][4]; int i1[2][4];
#pragma unroll
  for (int s = 0; s < 2; ++s)
#pragma unroll
    for (int i = 0; i < 4; ++i) {
      s1[s][i] = 3.402823466e+38f; s2[s][i] = 3.402823466e+38f; i1[s][i] = 0;
    }

#define STAGE(ct_, bi_)                                                             \
  { _Pragma("unroll")                                                               \
    for (int i_ = 0; i_ < 2; ++i_) {                                                \
      int c_  = wave * 2 + i_;                                                      \
      int p_  = c_ >> 2, ks_ = c_ & 3;                                              \
      const short* gsrc_ = (p_ ? BlG : BhG) +                                       \
                           (size_t)(((ct_) * 4 + ks_) * 64 + lane) * 8;             \
      __builtin_amdgcn_global_load_lds(                                             \
          (const __attribute__((address_space(1))) void*)gsrc_,                     \
          (__attribute__((address_space(3))) void*)&Bbuf[bi_][c_][0], 16, 0, 0);    \
    } }

#define COMP(bi_, ct_)                                                              \
  { bf16x8 bh_c[4], bl_c[4];                                                        \
    _Pragma("unroll")                                                               \
    for (int ks_ = 0; ks_ < 4; ++ks_) {                                             \
      bh_c[ks_] = *reinterpret_cast<const bf16x8*>(&Bbuf[bi_][ks_][lane * 8]);      \
      bl_c[ks_] = *reinterpret_cast<const bf16x8*>(&Bbuf[bi_][4 + ks_][lane * 8]);  \
    }                                                                               \
    const int code_ = (ct_) * 16 + col;                                             \
    const float cn_ = CnS[code_];                                                   \
    __builtin_amdgcn_s_setprio(1);                                                  \
    _Pragma("unroll")                                                               \
    for (int set_ = 0; set_ < 2; ++set_) {                                          \
      f32x4 aA = (f32x4){0.f,0.f,0.f,0.f};                                          \
      f32x4 aB = (f32x4){0.f,0.f,0.f,0.f};                                          \
      f32x4 aC = (f32x4){0.f,0.f,0.f,0.f};                                          \
      _Pragma("unroll")                                                             \
      for (int ks_ = 0; ks_ < 4; ++ks_) {                                           \
        aA = __builtin_amdgcn_mfma_f32_16x16x32_bf16(ah[set_][ks_], bh_c[ks_], aA, 0,0,0); \
        aB = __builtin_amdgcn_mfma_f32_16x16x32_bf16(ah[set_][ks_], bl_c[ks_], aB, 0,0,0); \
        aC = __builtin_amdgcn_mfma_f32_16x16x32_bf16(al[set_][ks_], bh_c[ks_], aC, 0,0,0); \
      }                                                                             \
      _Pragma("unroll")                                                             \
      for (int reg_ = 0; reg_ < 4; ++reg_) {                                        \
        float S = fmaf(-2.0f, (aA[reg_] + aB[reg_]) + aC[reg_], cn_);               \
        if (S < s1[set_][reg_]) { s2[set_][reg_] = s1[set_][reg_];                  \
                                  s1[set_][reg_] = S; i1[set_][reg_] = code_; }     \
        else if (S < s2[set_][reg_]) { s2[set_][reg_] = S; }                        \
      }                                                                             \
    }                                                                               \
    __builtin_amdgcn_s_setprio(0); }

#define PHASE(t_, bi_)                                                              \
  { asm volatile("s_waitcnt vmcnt(4)" ::: "memory");                                \
    __builtin_amdgcn_s_barrier();                                                   \
    __builtin_amdgcn_sched_barrier(0);                                              \
    COMP(bi_, t_);                                                                  \
    STAGE(((t_) + 3) & 63, ((bi_) + 3) & 3); }

  __syncthreads();   // CnS visible
  STAGE(0, 0); STAGE(1, 1); STAGE(2, 2);
  for (int g = 0; g < NCT; g += 4) {
    PHASE(g + 0, 0);
    PHASE(g + 1, 1);
    PHASE(g + 2, 2);
    PHASE(g + 3, 3);
  }
#undef PHASE
#undef STAGE
#undef COMP

  // cross-lane (16-col group) min1/min2 merge
#pragma unroll
  for (int m = 1; m < 16; m <<= 1) {
#pragma unroll
    for (int set = 0; set < 2; ++set)
#pragma unroll
      for (int reg = 0; reg < 4; ++reg) {
        float os1 = __shfl_xor(s1[set][reg], m, 64);
        float os2 = __shfl_xor(s2[set][reg], m, 64);
        int   oi  = __shfl_xor(i1[set][reg], m, 64);
        if (os1 < s1[set][reg]) {
          s2[set][reg] = fminf(s1[set][reg], os2);
          s1[set][reg] = os1; i1[set][reg] = oi;
        } else {
          s2[set][reg] = fminf(s2[set][reg], os1);
        }
      }
  }

  if (col == 0) {
#pragma unroll
    for (int set = 0; set < 2; ++set)
#pragma unroll
      for (int reg = 0; reg < 4; ++reg) {
        int row = wave * 32 + set * 16 + (lane >> 4) * 4 + reg;
        size_t m = (size_t)baseRow + row;
        out_iF[m]  = (float)i1[set][reg];
        out_gap[m] = s2[set][reg] - s1[set][reg];
      }
  }
}

// ---------------- kernel 2: COLLECT — build global hard-row list ----------------
__global__ __launch_bounds__(256) void vq_collect(
    const float* __restrict__ gap, int* __restrict__ cnt, int* __restrict__ list) {
  const int m = blockIdx.x * 256 + threadIdx.x;
  if (gap[m] < TAU) {
    int p = atomicAdd(cnt, 1);
    if (p < M_TOTAL - 1) list[p] = m;
  }
}

// ---------------- kernel 3a: FULL RESCAN via transposed codebook (coalesced) ----------
__global__ __launch_bounds__(256, 4) void vq_rescan_cbT(
    const float* __restrict__ z, const float4* __restrict__ cbT4,
    const float* __restrict__ Cn,
    const int* __restrict__ cnt, const int* __restrict__ list,
    float* __restrict__ out_iF) {
  __shared__ __align__(16) float Zs[D];
  __shared__ float sRed[256];
  __shared__ int   iRed[256];
  const int t = threadIdx.x;
  int n = *cnt; if (n > M_TOTAL - 1) n = M_TOTAL - 1;

  for (int it = blockIdx.x; it < n; it += gridDim.x) {
    const int row = list[it];
    if (t < 32) {
      reinterpret_cast<float4*>(Zs)[t] =
          reinterpret_cast<const float4*>(z + (size_t)row * D)[t];
    }
    __syncthreads();

    // exact numpy-fp32: 4 sequential-FMA chains (codes 4t..4t+3), d ascending;
    // loads cbT4[(d<<8)+t] are lane-contiguous -> 1KB coalesced wave-loads, L2-hit
    float a0 = 0.f, a1 = 0.f, a2 = 0.f, a3 = 0.f;
#pragma unroll 8
    for (int d = 0; d < D; ++d) {
      float  zv = Zs[d];                 // LDS broadcast
      float4 cv = cbT4[(d << 8) + t];
      a0 = fmaf(zv, cv.x, a0);
      a1 = fmaf(zv, cv.y, a1);
      a2 = fmaf(zv, cv.z, a2);
      a3 = fmaf(zv, cv.w, a3);
    }
    const float A = np_norm128(Zs);      // numpy pairwise-8 (broadcast reads)

    const int kb = t * 4;
    float bd = 3.402823466e+38f; int bi = 0;
    {  // ascending k, strict <: numpy first-occurrence
      float d0 = __fadd_rn(__fsub_rn(A, __fmul_rn(2.0f, a0)), Cn[kb + 0]);
      float d1 = __fadd_rn(__fsub_rn(A, __fmul_rn(2.0f, a1)), Cn[kb + 1]);
      float d2 = __fadd_rn(__fsub_rn(A, __fmul_rn(2.0f, a2)), Cn[kb + 2]);
      float d3 = __fadd_rn(__fsub_rn(A, __fmul_rn(2.0f, a3)), Cn[kb + 3]);
      if (d0 < bd) { bd = d0; bi = kb + 0; }
      if (d1 < bd) { bd = d1; bi = kb + 1; }
      if (d2 < bd) { bd = d2; bi = kb + 2; }
      if (d3 < bd) { bd = d3; bi = kb + 3; }
    }
    sRed[t] = bd; iRed[t] = bi;
    __syncthreads();
    for (int w = 128; w > 0; w >>= 1) {
      if (t < w) {
        float o = sRed[t + w]; int oi = iRed[t + w];
        if (o < sRed[t] || (o == sRed[t] && oi < iRed[t])) { sRed[t] = o; iRed[t] = oi; }
      }
      __syncthreads();
    }
    if (t == 0) out_iF[row] = (float)iRed[0];
    __syncthreads();   // protect Zs before next iteration
  }
}

// ---------------- kernel 3b: FALLBACK rescan (R18 verbatim, used if ws too small) -----
__global__ __launch_bounds__(256, 4) void vq_rescan_full(
    const float* __restrict__ z, const float* __restrict__ cb,
    const float* __restrict__ Cn,
    const int* __restrict__ cnt, const int* __restrict__ list,
    float* __restrict__ out_iF) {
  __shared__ __align__(16) float Zs[D];
  __shared__ float sRed[256];
  __shared__ int   iRed[256];
  const int t = threadIdx.x;
  int n = *cnt; if (n > M_TOTAL - 1) n = M_TOTAL - 1;

  for (int it = blockIdx.x; it < n; it += gridDim.x) {
    const int row = list[it];
    if (t < 32) {
      reinterpret_cast<float4*>(Zs)[t] =
          reinterpret_cast<const float4*>(z + (size_t)row * D)[t];
    }
    __syncthreads();

    const float4* zp4 = reinterpret_cast<const float4*>(Zs);
    const int kb = t * 4;
    const float4* c0 = reinterpret_cast<const float4*>(cb + (size_t)(kb + 0) * D);
    const float4* c1 = reinterpret_cast<const float4*>(cb + (size_t)(kb + 1) * D);
    const float4* c2 = reinterpret_cast<const float4*>(cb + (size_t)(kb + 2) * D);
    const float4* c3 = reinterpret_cast<const float4*>(cb + (size_t)(kb + 3) * D);
    float a0 = 0.f, a1 = 0.f, a2 = 0.f, a3 = 0.f;
#pragma unroll 8
    for (int d4 = 0; d4 < 32; ++d4) {
      float4 zv = zp4[d4];
      float4 v0 = c0[d4], v1 = c1[d4], v2 = c2[d4], v3 = c3[d4];
      a0 = fmaf(zv.x, v0.x, a0); a0 = fmaf(zv.y, v0.y, a0);
      a0 = fmaf(zv.z, v0.z, a0); a0 = fmaf(zv.w, v0.w, a0);
      a1 = fmaf(zv.x, v1.x, a1); a1 = fmaf(zv.y, v1.y, a1);
      a1 = fmaf(zv.z, v1.z, a1); a1 = fmaf(zv.w, v1.w, a1);
      a2 = fmaf(zv.x, v2.x, a2); a2 = fmaf(zv.y, v2.y, a2);
      a2 = fmaf(zv.z, v2.z, a2); a2 = fmaf(zv.w, v2.w, a2);
      a3 = fmaf(zv.x, v3.x, a3); a3 = fmaf(zv.y, v3.y, a3);
      a3 = fmaf(zv.z, v3.z, a3); a3 = fmaf(zv.w, v3.w, a3);
    }
    const float A = np_norm128(Zs);

    float bd = 3.402823466e+38f; int bi = 0;
    {
      float d0 = __fadd_rn(__fsub_rn(A, __fmul_rn(2.0f, a0)), Cn[kb + 0]);
      float d1 = __fadd_rn(__fsub_rn(A, __fmul_rn(2.0f, a1)), Cn[kb + 1]);
      float d2 = __fadd_rn(__fsub_rn(A, __fmul_rn(2.0f, a2)), Cn[kb + 2]);
      float d3 = __fadd_rn(__fsub_rn(A, __fmul_rn(2.0f, a3)), Cn[kb + 3]);
      if (d0 < bd) { bd = d0; bi = kb + 0; }
      if (d1 < bd) { bd = d1; bi = kb + 1; }
      if (d2 < bd) { bd = d2; bi = kb + 2; }
      if (d3 < bd) { bd = d3; bi = kb + 3; }
    }
    sRed[t] = bd; iRed[t] = bi;
    __syncthreads();
    for (int w = 128; w > 0; w >>= 1) {
      if (t < w) {
        float o = sRed[t + w]; int oi = iRed[t + w];
        if (o < sRed[t] || (o == sRed[t] && oi < iRed[t])) { sRed[t] = o; iRed[t] = oi; }
      }
      __syncthreads();
    }
    if (t == 0) out_iF[row] = (float)iRed[0];
    __syncthreads();
  }
}

// ---------------- kernel 4: EPILOGUE — pure-BW gather/STE/loss (validated absmax 0) ---
__global__ __launch_bounds__(256) void vq_epi(
    const float* __restrict__ z, const float* __restrict__ cb,
    const float* __restrict__ out_iF,
    float* __restrict__ out_zq, float* __restrict__ out_q,
    float* __restrict__ out_c) {
  const int t = threadIdx.x;
  const int r = t >> 2, q = t & 3;
  const size_t m = (size_t)blockIdx.x * 64 + r;   // grid 1024
  const int idx = (int)out_iF[m];
  const float4* cq = reinterpret_cast<const float4*>(cb + (size_t)idx * D);
  const float4* zr = reinterpret_cast<const float4*>(z + m * D);
  float4*       o4 = reinterpret_cast<float4*>(out_zq + m * D);
  float sum = 0.f;
#pragma unroll
  for (int e = 0; e < 8; ++e) {
    int d4 = q * 8 + e;
    float4 cv = cq[d4];
    float4 zv = zr[d4];
    float dx = cv.x - zv.x, dy = cv.y - zv.y, dz = cv.z - zv.z, dw = cv.w - zv.w;
    float4 st;
    st.x = zv.x + dx; st.y = zv.y + dy; st.z = zv.z + dz; st.w = zv.w + dw;
    o4[d4] = st;
    sum = fmaf(dx, dx, sum); sum = fmaf(dy, dy, sum);
    sum = fmaf(dz, dz, sum); sum = fmaf(dw, dw, sum);
  }
  sum += __shfl_xor(sum, 1, 64);
  sum += __shfl_xor(sum, 2, 64);
  if (q == 0) {
    float lv = sum * 0.0078125f;   // /128
    out_q[m] = lv;
    out_c[m] = lv;
  }
}

// ---------------- FALLBACK main: R4 kernel verbatim (validated, ~320 us) ---------------
__global__ __launch_bounds__(256) void vq_main_fp32(
    const float* __restrict__ z, const float* __restrict__ cb,
    const float* __restrict__ Cn,
    float* __restrict__ out_zq, float* __restrict__ out_q,
    float* __restrict__ out_c, float* __restrict__ out_i) {
  __shared__ float Zt[64 * D];
  __shared__ float Ct[64 * D];
  __shared__ float Arow[64];
  __shared__ int   idxArr[64];

  const int t  = threadIdx.x;
  const int ty = t >> 4;
  const int tx = t & 15;
  const int baseRow = blockIdx.x * 64;

  for (int s = t; s < 64 * (D / 4); s += 256) {
    int r = s >> 5, d4 = s & 31;
    float4 v = reinterpret_cast<const float4*>(z)[(size_t)(baseRow + r) * (D / 4) + d4];
    int colx = d4 ^ (r & 7);
    *reinterpret_cast<float4*>(&Zt[r * D + colx * 4]) = v;
  }
  __syncthreads();

  if (t < 64) {
    const int rs = t & 7;
    float r8[8];
#pragma unroll
    for (int j = 0; j < 8; ++j) {
      float v = Zt[t * D + (((j >> 2) ^ rs) << 2) + (j & 3)];
      r8[j] = __fmul_rn(v, v);
    }
    for (int i = 8; i < D; i += 8) {
#pragma unroll
      for (int j = 0; j < 8; ++j) {
        int d = i + j;
        float v = Zt[t * D + (((d >> 2) ^ rs) << 2) + (d & 3)];
        r8[j] = __fadd_rn(r8[j], __fmul_rn(v, v));
      }
    }
    Arow[t] = __fadd_rn(__fadd_rn(__fadd_rn(r8[0], r8[1]), __fadd_rn(r8[2], r8[3])),
                        __fadd_rn(__fadd_rn(r8[4], r8[5]), __fadd_rn(r8[6], r8[7])));
  }

  float s1[4]; int i1[4];
#pragma unroll
  for (int i = 0; i < 4; ++i) { s1[i] = 3.402823466e+38f; i1[i] = 0; }

  const int zsw = ty & 7;
  const int csw = tx & 7;

  for (int kt = 0; kt < 16; ++kt) {
    __syncthreads();
    for (int s = t; s < 64 * (D / 4); s += 256) {
      int r = s >> 5, d4 = s & 31;
      float4 v = reinterpret_cast<const float4*>(cb)[(size_t)(kt * 64 + r) * (D / 4) + d4];
      int colx = d4 ^ (r & 7);
      *reinterpret_cast<float4*>(&Ct[r * D + colx * 4]) = v;
    }
    __syncthreads();

    float acc[4][4];
#pragma unroll
    for (int i = 0; i < 4; ++i)
#pragma unroll
      for (int j = 0; j < 4; ++j) acc[i][j] = 0.f;

    for (int d4 = 0; d4 < 32; ++d4) {
      float4 za[4], cv[4];
      int zc = (d4 ^ zsw) * 4;
      int cc = (d4 ^ csw) * 4;
#pragma unroll
      for (int i = 0; i < 4; ++i)
        za[i] = *reinterpret_cast<const float4*>(&Zt[(ty + 16 * i) * D + zc]);
#pragma unroll
      for (int j = 0; j < 4; ++j)
        cv[j] = *reinterpret_cast<const float4*>(&Ct[(tx + 16 * j) * D + cc]);
#pragma unroll
      for (int i = 0; i < 4; ++i)
#pragma unroll
        for (int j = 0; j < 4; ++j) {
          acc[i][j] = fmaf(za[i].x, cv[j].x, acc[i][j]);
          acc[i][j] = fmaf(za[i].y, cv[j].y, acc[i][j]);
          acc[i][j] = fmaf(za[i].z, cv[j].z, acc[i][j]);
          acc[i][j] = fmaf(za[i].w, cv[j].w, acc[i][j]);
        }
    }

    float ch[4]; int kg[4];
#pragma unroll
    for (int j = 0; j < 4; ++j) {
      kg[j] = kt * 64 + tx + 16 * j;
      ch[j] = Cn[kg[j]];
    }
#pragma unroll
    for (int i = 0; i < 4; ++i) {
      float a = Arow[ty + 16 * i];
#pragma unroll
      for (int j = 0; j < 4; ++j) {
        float dist = __fadd_rn(__fsub_rn(a, __fmul_rn(2.0f, acc[i][j])), ch[j]);
        if (dist < s1[i]) { s1[i] = dist; i1[i] = kg[j]; }
      }
    }
  }

#pragma unroll
  for (int m = 1; m < 16; m <<= 1) {
#pragma unroll
    for (int i = 0; i < 4; ++i) {
      float os = __shfl_xor(s1[i], m, 64);
      int   oi = __shfl_xor(i1[i], m, 64);
      if (os < s1[i] || (os == s1[i] && oi < i1[i])) { s1[i] = os; i1[i] = oi; }
    }
  }

  if (tx == 0) {
#pragma unroll
    for (int i = 0; i < 4; ++i) idxArr[ty + 16 * i] = i1[i];
  }
  __syncthreads();

  {
    int r = t >> 2, q = t & 3;
    int idx = idxArr[r];
    size_t m = (size_t)baseRow + r;
    const float4* cq = reinterpret_cast<const float4*>(cb + (size_t)idx * D);
    const float4* zr = reinterpret_cast<const float4*>(z + m * D);
    float4*       o4 = reinterpret_cast<float4*>(out_zq + m * D);
    float sum = 0.f;
#pragma unroll
    for (int e = 0; e < 8; ++e) {
      int d4 = q * 8 + e;
      float4 cv = cq[d4];
      float4 zv = zr[d4];
      float dx = cv.x - zv.x, dy = cv.y - zv.y, dz = cv.z - zv.z, dw = cv.w - zv.w;
      float4 st;
      st.x = zv.x + dx; st.y = zv.y + dy; st.z = zv.z + dz; st.w = zv.w + dw;
      o4[d4] = st;
      sum = fmaf(dx, dx, sum); sum = fmaf(dy, dy, sum);
      sum = fmaf(dz, dz, sum); sum = fmaf(dw, dw, sum);
    }
    sum += __shfl_xor(sum, 1, 64);
    sum += __shfl_xor(sum, 2, 64);
    if (q == 0) {
      float lv = sum * 0.0078125f;
      out_q[m] = lv;
      out_c[m] = lv;
      out_i[m] = (float)idx;
    }
  }
}

extern "C" void kernel_launch(void* const* d_in, const int* in_sizes, int n_in,
                              void* d_out, int out_size, void* d_ws, size_t ws_size,
                              hipStream_t stream) {
  const float* z  = (const float*)d_in[0];   // [16,4096,128] fp32
  const float* cb = (const float*)d_in[1];   // [1024,128] fp32

  float* out0 = (float*)d_out;               // z_q_ste  [M,128]
  float* out1 = out0 + (size_t)M_TOTAL * D;  // quant_loss [M]
  float* out2 = out1 + M_TOTAL;              // commit_loss [M]
  float* out3 = out2 + M_TOTAL;              // indices (as float) [M]

  float* Cn = (float*)((char*)d_ws + WS_CN);
  // scratch: gap in out1, cnt+list in out2 (both overwritten by epi)
  int* cnt  = (int*)out2;
  int* list = (int*)out2 + 1;

  vq_prep<<<(K + 255) / 256, 256, 0, stream>>>(cb, Cn, cnt);

  if (ws_size >= WS_REQ) {
    short* Bh = (short*)((char*)d_ws + WS_BH);
    short* Bl = (short*)((char*)d_ws + WS_BL);
    vq_frag<<<64, 256, 0, stream>>>(cb, Bh, Bl);
    vq_score<<<M_TOTAL / BM, 256, 0, stream>>>(z, Cn, Bh, Bl, out3, out1);
    vq_collect<<<M_TOTAL / 256, 256, 0, stream>>>(out1, cnt, list);
    if (ws_size >= WS_REQ2) {
      float4* cbT4 = (float4*)((char*)d_ws + WS_CBT);
      vq_trans<<<128, 256, 0, stream>>>(cb, cbT4);
      vq_rescan_cbT<<<1024, 256, 0, stream>>>(z, cbT4, Cn, cnt, list, out3);
    } else {
      vq_rescan_full<<<1024, 256, 0, stream>>>(z, cb, Cn, cnt, list, out3);
    }
    vq_epi<<<M_TOTAL / 64, 256, 0, stream>>>(z, cb, out3, out0, out1, out2);
  } else {
    vq_main_fp32<<<M_TOTAL / 64, 256, 0, stream>>>(z, cb, Cn, out0, out1, out2, out3);
  }
}

// Round 20
// 115.263 us; speedup vs baseline: 2.4818x; 1.0732x over previous
//
#include <hip/hip_runtime.h>
#include <hip/hip_bf16.h>

namespace {
constexpr int D       = 128;
constexpr int K       = 1024;
constexpr int M_TOTAL = 65536;   // 16 * 4096
constexpr int BM      = 128;     // rows per score-block: 4 waves x 32 rows
constexpr int NCT     = K / 16;  // 64 code-tiles of 16 codes
constexpr float TAU   = 5.0e-5f; // > 2*(scorer err) + 2*(numpy quantization span)
// d_ws layout
constexpr size_t WS_CN   = 0;                    // float[1024]     (4 KB)
constexpr size_t WS_BH   = 4096;                 // short[131072]   (256 KB)
constexpr size_t WS_BL   = 4096 + 262144;        // short[131072]   (256 KB)
constexpr size_t WS_REQ  = 4096 + 2 * 262144;    // 528,384 B (confirmed, R11-R19)
constexpr size_t WS_CBT  = WS_REQ;               // float4[32768]   (512 KB)
constexpr size_t WS_REQ2 = WS_REQ + 524288;      // 1,052,672 B (confirmed, R19)
}

typedef short bf16x8 __attribute__((ext_vector_type(8)));
typedef float f32x4  __attribute__((ext_vector_type(4)));

static __device__ __forceinline__ unsigned short bfbits(float x) {
  __hip_bfloat16 h = __float2bfloat16(x);   // RNE
  return *reinterpret_cast<unsigned short*>(&h);
}
static __device__ __forceinline__ float bfhi2f(unsigned short h) {
  return __uint_as_float(((unsigned)h) << 16);
}
static __device__ __forceinline__ void split8(float4 a, float4 b,
                                              bf16x8& ph, bf16x8& pl) {
  float v[8] = {a.x, a.y, a.z, a.w, b.x, b.y, b.z, b.w};
#pragma unroll
  for (int e = 0; e < 8; ++e) {
    unsigned short h = bfbits(v[e]);
    unsigned short l = bfbits(v[e] - bfhi2f(h));
    ph[e] = (short)h;
    pl[e] = (short)l;
  }
}
// numpy pairwise-8 row norm of 128 consecutive floats (R4-validated, bit-exact)
static __device__ __forceinline__ float np_norm128(const float* p) {
  float r8[8];
#pragma unroll
  for (int j = 0; j < 8; ++j) r8[j] = __fmul_rn(p[j], p[j]);
  for (int i = 8; i < D; i += 8) {
#pragma unroll
    for (int j = 0; j < 8; ++j)
      r8[j] = __fadd_rn(r8[j], __fmul_rn(p[i + j], p[i + j]));
  }
  return __fadd_rn(__fadd_rn(__fadd_rn(r8[0], r8[1]), __fadd_rn(r8[2], r8[3])),
                   __fadd_rn(__fadd_rn(r8[4], r8[5]), __fadd_rn(r8[6], r8[7])));
}

// ---------------- merged prep: Cn + cnt=0 | bf16 planes | transposed codebook ---------
// blocks 0..3: Cn (numpy-pairwise norms); 4..67: fragment planes; 68..195: cbT4.
// All read only cb; writes disjoint; no inter-block deps.
__global__ void vq_prep_all(const float* __restrict__ cb, float* __restrict__ Cn,
                            int* __restrict__ cnt,
                            short* __restrict__ Bh, short* __restrict__ Bl,
                            float4* __restrict__ cbT4) {
  const int b = blockIdx.x, t = threadIdx.x;
  if (b < 4) {
    int k = b * 256 + t;
    if (b == 0 && t == 0) *cnt = 0;
    if (k < K) Cn[k] = np_norm128(cb + (size_t)k * D);
  } else if (b < 68) {
    int g = (b - 4) * 256 + t;                  // 0 .. 16383
    int code = (g >> 8) * 16 + (g & 15);
    int d0   = ((g >> 6) & 3) * 32 + ((g >> 4) & 3) * 8;
    const float* p = cb + (size_t)code * D + d0;
    float4 a = *reinterpret_cast<const float4*>(p);
    float4 bb = *reinterpret_cast<const float4*>(p + 4);
    bf16x8 ph, pl;
    split8(a, bb, ph, pl);
    *reinterpret_cast<bf16x8*>(Bh + (size_t)g * 8) = ph;
    *reinterpret_cast<bf16x8*>(Bl + (size_t)g * 8) = pl;
  } else {
    int g = (b - 68) * 256 + t;                 // 0 .. 32767
    int d = g >> 8, tt = g & 255;
    float4 v;
    v.x = cb[(size_t)(4 * tt + 0) * D + d];
    v.y = cb[(size_t)(4 * tt + 1) * D + d];
    v.z = cb[(size_t)(4 * tt + 2) * D + d];
    v.w = cb[(size_t)(4 * tt + 3) * D + d];
    cbT4[g] = v;
  }
}

// ---------------- kernel 1: SCORE — 8-deep counted-vmcnt pipeline + fused flagging ----
__global__ __launch_bounds__(256, 2) void vq_score(
    const float* __restrict__ z, const float* __restrict__ Cn,
    const short* __restrict__ BhG, const short* __restrict__ BlG,
    float* __restrict__ out_iF, int* __restrict__ cnt, int* __restrict__ list) {
  __shared__ __align__(16) short Bbuf[8][8][512];   // 64 KB, 8 single-tile buffers
  __shared__ float CnS[K];                           // 4 KB

  const int t    = threadIdx.x;
  const int wave = t >> 6;
  const int lane = t & 63;
  const int col  = lane & 15;
  const int baseRow = blockIdx.x * BM;

  for (int i = t; i < K; i += 256) CnS[i] = Cn[i];

  bf16x8 ah[2][4], al[2][4];
#pragma unroll
  for (int set = 0; set < 2; ++set) {
    const float* zL = z + (size_t)(baseRow + wave * 32 + set * 16 + col) * D + (lane >> 4) * 8;
#pragma unroll
    for (int ks = 0; ks < 4; ++ks) {
      float4 a = *reinterpret_cast<const float4*>(zL + ks * 32);
      float4 b = *reinterpret_cast<const float4*>(zL + ks * 32 + 4);
      split8(a, b, ah[set][ks], al[set][ks]);
    }
  }

  float s1[2][4], s2[2][4]; int i1[2][4];
#pragma unroll
  for (int s = 0; s < 2; ++s)
#pragma unroll
    for (int i = 0; i < 4; ++i) {
      s1[s][i] = 3.402823466e+38f; s2[s][i] = 3.402823466e+38f; i1[s][i] = 0;
    }

#define STAGE(ct_, bi_)                                                             \
  { _Pragma("unroll")                                                               \
    for (int i_ = 0; i_ < 2; ++i_) {                                                \
      int c_  = wave * 2 + i_;                                                      \
      int p_  = c_ >> 2, ks_ = c_ & 3;                                              \
      const short* gsrc_ = (p_ ? BlG : BhG) +                                       \
                           (size_t)(((ct_) * 4 + ks_) * 64 + lane) * 8;             \
      __builtin_amdgcn_global_load_lds(                                             \
          (const __attribute__((address_space(1))) void*)gsrc_,                     \
          (__attribute__((address_space(3))) void*)&Bbuf[bi_][c_][0], 16, 0, 0);    \
    } }

#define COMP(bi_, ct_)                                                              \
  { bf16x8 bh_c[4], bl_c[4];                                                        \
    _Pragma("unroll")                                                               \
    for (int ks_ = 0; ks_ < 4; ++ks_) {                                             \
      bh_c[ks_] = *reinterpret_cast<const bf16x8*>(&Bbuf[bi_][ks_][lane * 8]);      \
      bl_c[ks_] = *reinterpret_cast<const bf16x8*>(&Bbuf[bi_][4 + ks_][lane * 8]);  \
    }                                                                               \
    const int code_ = (ct_) * 16 + col;                                             \
    const float cn_ = CnS[code_];                                                   \
    __builtin_amdgcn_s_setprio(1);                                                  \
    _Pragma("unroll")                                                               \
    for (int set_ = 0; set_ < 2; ++set_) {                                          \
      f32x4 aA = (f32x4){0.f,0.f,0.f,0.f};                                          \
      f32x4 aB = (f32x4){0.f,0.f,0.f,0.f};                                          \
      f32x4 aC = (f32x4){0.f,0.f,0.f,0.f};                                          \
      _Pragma("unroll")                                                             \
      for (int ks_ = 0; ks_ < 4; ++ks_) {                                           \
        aA = __builtin_amdgcn_mfma_f32_16x16x32_bf16(ah[set_][ks_], bh_c[ks_], aA, 0,0,0); \
        aB = __builtin_amdgcn_mfma_f32_16x16x32_bf16(ah[set_][ks_], bl_c[ks_], aB, 0,0,0); \
        aC = __builtin_amdgcn_mfma_f32_16x16x32_bf16(al[set_][ks_], bh_c[ks_], aC, 0,0,0); \
      }                                                                             \
      _Pragma("unroll")                                                             \
      for (int reg_ = 0; reg_ < 4; ++reg_) {                                        \
        float S = fmaf(-2.0f, (aA[reg_] + aB[reg_]) + aC[reg_], cn_);               \
        if (S < s1[set_][reg_]) { s2[set_][reg_] = s1[set_][reg_];                  \
                                  s1[set_][reg_] = S; i1[set_][reg_] = code_; }     \
        else if (S < s2[set_][reg_]) { s2[set_][reg_] = S; }                        \
      }                                                                             \
    }                                                                               \
    __builtin_amdgcn_s_setprio(0); }

  // 8-deep: 7 tiles staged ahead (14 loads/thread); vmcnt(12) waits only the oldest
  // tile's 2 loads (6 tiles stay in flight). Wrap-staging keeps the count invariant
  // (same safety argument as the validated 4-deep: target buf last used 1 phase ago).
#define PHASE(t_, bi_)                                                              \
  { asm volatile("s_waitcnt vmcnt(12)" ::: "memory");                               \
    __builtin_amdgcn_s_barrier();                                                   \
    __builtin_amdgcn_sched_barrier(0);                                              \
    COMP(bi_, t_);                                                                  \
    STAGE(((t_) + 7) & 63, ((bi_) + 7) & 7); }

  __syncthreads();   // CnS visible
  STAGE(0, 0); STAGE(1, 1); STAGE(2, 2); STAGE(3, 3);
  STAGE(4, 4); STAGE(5, 5); STAGE(6, 6);
  for (int g = 0; g < NCT; g += 8) {
    PHASE(g + 0, 0);
    PHASE(g + 1, 1);
    PHASE(g + 2, 2);
    PHASE(g + 3, 3);
    PHASE(g + 4, 4);
    PHASE(g + 5, 5);
    PHASE(g + 6, 6);
    PHASE(g + 7, 7);
  }
#undef PHASE
#undef STAGE
#undef COMP

  // cross-lane (16-col group) min1/min2 merge
#pragma unroll
  for (int m = 1; m < 16; m <<= 1) {
#pragma unroll
    for (int set = 0; set < 2; ++set)
#pragma unroll
      for (int reg = 0; reg < 4; ++reg) {
        float os1 = __shfl_xor(s1[set][reg], m, 64);
        float os2 = __shfl_xor(s2[set][reg], m, 64);
        int   oi  = __shfl_xor(i1[set][reg], m, 64);
        if (os1 < s1[set][reg]) {
          s2[set][reg] = fminf(s1[set][reg], os2);
          s1[set][reg] = os1; i1[set][reg] = oi;
        } else {
          s2[set][reg] = fminf(s2[set][reg], os1);
        }
      }
  }

  // write index + fused hard-row flagging (collect kernel eliminated)
  if (col == 0) {
#pragma unroll
    for (int set = 0; set < 2; ++set)
#pragma unroll
      for (int reg = 0; reg < 4; ++reg) {
        int row = wave * 32 + set * 16 + (lane >> 4) * 4 + reg;
        size_t m = (size_t)baseRow + row;
        out_iF[m] = (float)i1[set][reg];
        if (s2[set][reg] - s1[set][reg] < TAU) {
          int p = atomicAdd(cnt, 1);
          if (p < M_TOTAL - 1) list[p] = (int)m;
        }
      }
  }
}

// ---------------- kernel 2: FULL RESCAN via transposed codebook (R19-validated) -------
__global__ __launch_bounds__(256, 4) void vq_rescan_cbT(
    const float* __restrict__ z, const float4* __restrict__ cbT4,
    const float* __restrict__ Cn,
    const int* __restrict__ cnt, const int* __restrict__ list,
    float* __restrict__ out_iF) {
  __shared__ __align__(16) float Zs[D];
  __shared__ float sRed[256];
  __shared__ int   iRed[256];
  const int t = threadIdx.x;
  int n = *cnt; if (n > M_TOTAL - 1) n = M_TOTAL - 1;

  for (int it = blockIdx.x; it < n; it += gridDim.x) {
    const int row = list[it];
    if (t < 32) {
      reinterpret_cast<float4*>(Zs)[t] =
          reinterpret_cast<const float4*>(z + (size_t)row * D)[t];
    }
    __syncthreads();

    float a0 = 0.f, a1 = 0.f, a2 = 0.f, a3 = 0.f;
#pragma unroll 8
    for (int d = 0; d < D; ++d) {
      float  zv = Zs[d];                 // LDS broadcast
      float4 cv = cbT4[(d << 8) + t];    // lane-contiguous, L2-hit
      a0 = fmaf(zv, cv.x, a0);
      a1 = fmaf(zv, cv.y, a1);
      a2 = fmaf(zv, cv.z, a2);
      a3 = fmaf(zv, cv.w, a3);
    }
    const float A = np_norm128(Zs);

    const int kb = t * 4;
    float bd = 3.402823466e+38f; int bi = 0;
    {  // ascending k, strict <: numpy first-occurrence
      float d0 = __fadd_rn(__fsub_rn(A, __fmul_rn(2.0f, a0)), Cn[kb + 0]);
      float d1 = __fadd_rn(__fsub_rn(A, __fmul_rn(2.0f, a1)), Cn[kb + 1]);
      float d2 = __fadd_rn(__fsub_rn(A, __fmul_rn(2.0f, a2)), Cn[kb + 2]);
      float d3 = __fadd_rn(__fsub_rn(A, __fmul_rn(2.0f, a3)), Cn[kb + 3]);
      if (d0 < bd) { bd = d0; bi = kb + 0; }
      if (d1 < bd) { bd = d1; bi = kb + 1; }
      if (d2 < bd) { bd = d2; bi = kb + 2; }
      if (d3 < bd) { bd = d3; bi = kb + 3; }
    }
    sRed[t] = bd; iRed[t] = bi;
    __syncthreads();
    for (int w = 128; w > 0; w >>= 1) {
      if (t < w) {
        float o = sRed[t + w]; int oi = iRed[t + w];
        if (o < sRed[t] || (o == sRed[t] && oi < iRed[t])) { sRed[t] = o; iRed[t] = oi; }
      }
      __syncthreads();
    }
    if (t == 0) out_iF[row] = (float)iRed[0];
    __syncthreads();   // protect Zs before next iteration
  }
}

// ---------------- kernel 3: EPILOGUE — pure-BW gather/STE/loss (validated absmax 0) ---
__global__ __launch_bounds__(256) void vq_epi(
    const float* __restrict__ z, const float* __restrict__ cb,
    const float* __restrict__ out_iF,
    float* __restrict__ out_zq, float* __restrict__ out_q,
    float* __restrict__ out_c) {
  const int t = threadIdx.x;
  const int r = t >> 2, q = t & 3;
  const size_t m = (size_t)blockIdx.x * 64 + r;   // grid 1024
  const int idx = (int)out_iF[m];
  const float4* cq = reinterpret_cast<const float4*>(cb + (size_t)idx * D);
  const float4* zr = reinterpret_cast<const float4*>(z + m * D);
  float4*       o4 = reinterpret_cast<float4*>(out_zq + m * D);
  float sum = 0.f;
#pragma unroll
  for (int e = 0; e < 8; ++e) {
    int d4 = q * 8 + e;
    float4 cv = cq[d4];
    float4 zv = zr[d4];
    float dx = cv.x - zv.x, dy = cv.y - zv.y, dz = cv.z - zv.z, dw = cv.w - zv.w;
    float4 st;
    st.x = zv.x + dx; st.y = zv.y + dy; st.z = zv.z + dz; st.w = zv.w + dw;
    o4[d4] = st;
    sum = fmaf(dx, dx, sum); sum = fmaf(dy, dy, sum);
    sum = fmaf(dz, dz, sum); sum = fmaf(dw, dw, sum);
  }
  sum += __shfl_xor(sum, 1, 64);
  sum += __shfl_xor(sum, 2, 64);
  if (q == 0) {
    float lv = sum * 0.0078125f;   // /128
    out_q[m] = lv;
    out_c[m] = lv;
  }
}

// ---------------- FALLBACK main: R4 kernel verbatim (validated, ~320 us) ---------------
__global__ __launch_bounds__(256) void vq_main_fp32(
    const float* __restrict__ z, const float* __restrict__ cb,
    const float* __restrict__ Cn,
    float* __restrict__ out_zq, float* __restrict__ out_q,
    float* __restrict__ out_c, float* __restrict__ out_i) {
  __shared__ float Zt[64 * D];
  __shared__ float Ct[64 * D];
  __shared__ float Arow[64];
  __shared__ int   idxArr[64];

  const int t  = threadIdx.x;
  const int ty = t >> 4;
  const int tx = t & 15;
  const int baseRow = blockIdx.x * 64;

  for (int s = t; s < 64 * (D / 4); s += 256) {
    int r = s >> 5, d4 = s & 31;
    float4 v = reinterpret_cast<const float4*>(z)[(size_t)(baseRow + r) * (D / 4) + d4];
    int colx = d4 ^ (r & 7);
    *reinterpret_cast<float4*>(&Zt[r * D + colx * 4]) = v;
  }
  __syncthreads();

  if (t < 64) {
    const int rs = t & 7;
    float r8[8];
#pragma unroll
    for (int j = 0; j < 8; ++j) {
      float v = Zt[t * D + (((j >> 2) ^ rs) << 2) + (j & 3)];
      r8[j] = __fmul_rn(v, v);
    }
    for (int i = 8; i < D; i += 8) {
#pragma unroll
      for (int j = 0; j < 8; ++j) {
        int d = i + j;
        float v = Zt[t * D + (((d >> 2) ^ rs) << 2) + (d & 3)];
        r8[j] = __fadd_rn(r8[j], __fmul_rn(v, v));
      }
    }
    Arow[t] = __fadd_rn(__fadd_rn(__fadd_rn(r8[0], r8[1]), __fadd_rn(r8[2], r8[3])),
                        __fadd_rn(__fadd_rn(r8[4], r8[5]), __fadd_rn(r8[6], r8[7])));
  }

  float s1[4]; int i1[4];
#pragma unroll
  for (int i = 0; i < 4; ++i) { s1[i] = 3.402823466e+38f; i1[i] = 0; }

  const int zsw = ty & 7;
  const int csw = tx & 7;

  for (int kt = 0; kt < 16; ++kt) {
    __syncthreads();
    for (int s = t; s < 64 * (D / 4); s += 256) {
      int r = s >> 5, d4 = s & 31;
      float4 v = reinterpret_cast<const float4*>(cb)[(size_t)(kt * 64 + r) * (D / 4) + d4];
      int colx = d4 ^ (r & 7);
      *reinterpret_cast<float4*>(&Ct[r * D + colx * 4]) = v;
    }
    __syncthreads();

    float acc[4][4];
#pragma unroll
    for (int i = 0; i < 4; ++i)
#pragma unroll
      for (int j = 0; j < 4; ++j) acc[i][j] = 0.f;

    for (int d4 = 0; d4 < 32; ++d4) {
      float4 za[4], cv[4];
      int zc = (d4 ^ zsw) * 4;
      int cc = (d4 ^ csw) * 4;
#pragma unroll
      for (int i = 0; i < 4; ++i)
        za[i] = *reinterpret_cast<const float4*>(&Zt[(ty + 16 * i) * D + zc]);
#pragma unroll
      for (int j = 0; j < 4; ++j)
        cv[j] = *reinterpret_cast<const float4*>(&Ct[(tx + 16 * j) * D + cc]);
#pragma unroll
      for (int i = 0; i < 4; ++i)
#pragma unroll
        for (int j = 0; j < 4; ++j) {
          acc[i][j] = fmaf(za[i].x, cv[j].x, acc[i][j]);
          acc[i][j] = fmaf(za[i].y, cv[j].y, acc[i][j]);
          acc[i][j] = fmaf(za[i].z, cv[j].z, acc[i][j]);
          acc[i][j] = fmaf(za[i].w, cv[j].w, acc[i][j]);
        }
    }

    float ch[4]; int kg[4];
#pragma unroll
    for (int j = 0; j < 4; ++j) {
      kg[j] = kt * 64 + tx + 16 * j;
      ch[j] = Cn[kg[j]];
    }
#pragma unroll
    for (int i = 0; i < 4; ++i) {
      float a = Arow[ty + 16 * i];
#pragma unroll
      for (int j = 0; j < 4; ++j) {
        float dist = __fadd_rn(__fsub_rn(a, __fmul_rn(2.0f, acc[i][j])), ch[j]);
        if (dist < s1[i]) { s1[i] = dist; i1[i] = kg[j]; }
      }
    }
  }

#pragma unroll
  for (int m = 1; m < 16; m <<= 1) {
#pragma unroll
    for (int i = 0; i < 4; ++i) {
      float os = __shfl_xor(s1[i], m, 64);
      int   oi = __shfl_xor(i1[i], m, 64);
      if (os < s1[i] || (os == s1[i] && oi < i1[i])) { s1[i] = os; i1[i] = oi; }
    }
  }

  if (tx == 0) {
#pragma unroll
    for (int i = 0; i < 4; ++i) idxArr[ty + 16 * i] = i1[i];
  }
  __syncthreads();

  {
    int r = t >> 2, q = t & 3;
    int idx = idxArr[r];
    size_t m = (size_t)baseRow + r;
    const float4* cq = reinterpret_cast<const float4*>(cb + (size_t)idx * D);
    const float4* zr = reinterpret_cast<const float4*>(z + m * D);
    float4*       o4 = reinterpret_cast<float4*>(out_zq + m * D);
    float sum = 0.f;
#pragma unroll
    for (int e = 0; e < 8; ++e) {
      int d4 = q * 8 + e;
      float4 cv = cq[d4];
      float4 zv = zr[d4];
      float dx = cv.x - zv.x, dy = cv.y - zv.y, dz = cv.z - zv.z, dw = cv.w - zv.w;
      float4 st;
      st.x = zv.x + dx; st.y = zv.y + dy; st.z = zv.z + dz; st.w = zv.w + dw;
      o4[d4] = st;
      sum = fmaf(dx, dx, sum); sum = fmaf(dy, dy, sum);
      sum = fmaf(dz, dz, sum); sum = fmaf(dw, dw, sum);
    }
    sum += __shfl_xor(sum, 1, 64);
    sum += __shfl_xor(sum, 2, 64);
    if (q == 0) {
      float lv = sum * 0.0078125f;
      out_q[m] = lv;
      out_c[m] = lv;
      out_i[m] = (float)idx;
    }
  }
}

extern "C" void kernel_launch(void* const* d_in, const int* in_sizes, int n_in,
                              void* d_out, int out_size, void* d_ws, size_t ws_size,
                              hipStream_t stream) {
  const float* z  = (const float*)d_in[0];   // [16,4096,128] fp32
  const float* cb = (const float*)d_in[1];   // [1024,128] fp32

  float* out0 = (float*)d_out;               // z_q_ste  [M,128]
  float* out1 = out0 + (size_t)M_TOTAL * D;  // quant_loss [M]
  float* out2 = out1 + M_TOTAL;              // commit_loss [M]
  float* out3 = out2 + M_TOTAL;              // indices (as float) [M]

  float* Cn = (float*)((char*)d_ws + WS_CN);
  int* cnt  = (int*)out2;                    // overwritten by epi afterwards
  int* list = (int*)out2 + 1;

  if (ws_size >= WS_REQ2) {
    short*  Bh   = (short*)((char*)d_ws + WS_BH);
    short*  Bl   = (short*)((char*)d_ws + WS_BL);
    float4* cbT4 = (float4*)((char*)d_ws + WS_CBT);
    vq_prep_all<<<196, 256, 0, stream>>>(cb, Cn, cnt, Bh, Bl, cbT4);
    vq_score<<<M_TOTAL / BM, 256, 0, stream>>>(z, Cn, Bh, Bl, out3, cnt, list);
    vq_rescan_cbT<<<1024, 256, 0, stream>>>(z, cbT4, Cn, cnt, list, out3);
    vq_epi<<<M_TOTAL / 64, 256, 0, stream>>>(z, cb, out3, out0, out1, out2);
  } else {
    // conservative fallback (R4-validated monolith)
    vq_prep_all<<<4, 256, 0, stream>>>(cb, Cn, cnt, nullptr, nullptr, nullptr);
    vq_main_fp32<<<M_TOTAL / 64, 256, 0, stream>>>(z, cb, Cn, out0, out1, out2, out3);
  }
}